// Round 5
// baseline (782.016 us; speedup 1.0000x reference)
//
#include <hip/hip_runtime.h>

#define NROWS 32768
#define DIM 256
#define KCODES 1024
#define DECAYF 0.99f
#define EPSF 1e-5f

// ---------------- workspace layout (bytes) ----------------
// keys:      u64[32768]     @ 0         (262144)  packed (distbits<<32)|idx, atomicMin
// counts:    int[1024]      @ 262144    (4096)
// embeds:    float[262144]  @ 266240    (1048576)
// loss_part: float[8192]    @ 1314816   (32768)
// enorm:     float[1024]    @ 1347584   (4096)
// total:     float[1]       @ 1351680   (4)

// ---------------- output layout (floats) ----------------
// quantized_st:      [0, 8388608)
// token_ids:         [8388608, 8421376)
// commitment_loss:   [8421376, 8421377)
// new_embedding:     [8421377, 8683521)
// new_cluster_size:  [8683521, 8684545)
// new_embedding_avg: [8684545, 8946689)

__global__ __launch_bounds__(256) void k_enorm(const float* __restrict__ e,
                                               float* __restrict__ enorm) {
    int w = threadIdx.x >> 6, lane = threadIdx.x & 63;
    int c = blockIdx.x * 4 + w;
    const float4 v = *(const float4*)&e[(size_t)c * DIM + lane * 4];
    float s = v.x * v.x + v.y * v.y + v.z * v.z + v.w * v.w;
#pragma unroll
    for (int m = 32; m; m >>= 1) s += __shfl_xor(s, m, 64);
    if (lane == 0) enorm[c] = s;
}

// Fused distance + argmin. Block = 256 threads (16 tx x 16 ty).
// Grid = 1024: blockIdx = rowblk*2 + half; each block scans 512 codes
// (its half) for 64 rows. Tile: 64 rows x 32 codes per kt step; e-tile in
// 32KB LDS (XOR-swizzled) -> 4 blocks/CU (vs 2 before), occupancy 50%.
// Per-(row,code) FMA order identical to the round-4 passing kernel
// (d4 = 0..63 sequential, x/y/z/w within) -> bit-exact distances.
// Cross-half argmin merge: order-preserving u64 key atomicMin; low 32 bits
// hold the code idx so exact ties pick the smaller idx (JAX argmin rule).
__global__ __launch_bounds__(256, 4) void k_dist(const float* __restrict__ x,
                                                 const float* __restrict__ e,
                                                 const float* __restrict__ enorm,
                                                 unsigned long long* __restrict__ keys) {
    __shared__ float es[32 * 256];  // 32 KB

    const int t = threadIdx.x;
    const int tx = t & 15, ty = t >> 4;
    const int lane = t & 63, w = t >> 6;
    const int half = blockIdx.x & 1;
    const int row0 = (blockIdx.x >> 1) * 64;
    const int cbase = half * 512;

    float best[4];
    int bestidx[4];
#pragma unroll
    for (int i = 0; i < 4; ++i) { best[i] = 3.0e38f; bestidx[i] = 0; }

    const float* xbase[4];
#pragma unroll
    for (int i = 0; i < 4; ++i)
        xbase[i] = x + (size_t)(row0 + ty + 16 * i) * DIM;

    const int txs = tx & 7;  // swizzle constant for this thread's e-rows

    for (int kt = 0; kt < 16; ++kt) {
        __syncthreads();
        // stage e tile: wave w stages codes w*8 .. w*8+7 (32 codes x 1KB)
#pragma unroll
        for (int r = 0; r < 8; ++r) {
            int c = w * 8 + r;
            float4 v = *(const float4*)
                &e[(size_t)(cbase + kt * 32 + c) * DIM + lane * 4];
            *(float4*)&es[c * DIM + ((lane ^ (c & 7)) << 2)] = v;
        }
        __syncthreads();

        float acc[4][2];
#pragma unroll
        for (int i = 0; i < 4; ++i)
#pragma unroll
            for (int j = 0; j < 2; ++j) acc[i][j] = 0.0f;

#pragma unroll 8
        for (int d4 = 0; d4 < 64; ++d4) {
            float4 xv[4], ev[2];
#pragma unroll
            for (int i = 0; i < 4; ++i)
                xv[i] = *(const float4*)(xbase[i] + (d4 << 2));
#pragma unroll
            for (int j = 0; j < 2; ++j) {
                int c = tx + 16 * j;
                ev[j] = *(const float4*)&es[c * DIM + ((d4 ^ txs) << 2)];
            }
#pragma unroll
            for (int i = 0; i < 4; ++i)
#pragma unroll
                for (int j = 0; j < 2; ++j)
                    acc[i][j] += xv[i].x * ev[j].x + xv[i].y * ev[j].y +
                                 xv[i].z * ev[j].z + xv[i].w * ev[j].w;
        }

#pragma unroll
        for (int j = 0; j < 2; ++j) {
            int c = cbase + kt * 32 + tx + 16 * j;
            float en = enorm[c];
#pragma unroll
            for (int i = 0; i < 4; ++i) {
                float dist = en - 2.0f * acc[i][j];
                if (dist < best[i] || (dist == best[i] && c < bestidx[i])) {
                    best[i] = dist;
                    bestidx[i] = c;
                }
            }
        }
    }

    // reduce min across the 16 tx-lanes sharing each row, then merge halves
#pragma unroll
    for (int i = 0; i < 4; ++i) {
        float v = best[i];
        int bi = bestidx[i];
#pragma unroll
        for (int m = 1; m < 16; m <<= 1) {
            float v2 = __shfl_xor(v, m, 64);
            int b2 = __shfl_xor(bi, m, 64);
            if (v2 < v || (v2 == v && b2 < bi)) { v = v2; bi = b2; }
        }
        if (tx == 0) {
            unsigned int fb = __float_as_uint(v);
            unsigned int key32 = (fb & 0x80000000u) ? ~fb : (fb | 0x80000000u);
            unsigned long long key =
                ((unsigned long long)key32 << 32) | (unsigned int)bi;
            atomicMin(&keys[row0 + ty + 16 * i], key);
        }
    }
}

// gather quantized rows, straight-through output, loss partials, EMA scatter
__global__ __launch_bounds__(256) void k_scatter(const float* __restrict__ x,
                                                 const float* __restrict__ e,
                                                 const unsigned long long* __restrict__ keys,
                                                 float* __restrict__ out_q,
                                                 float* __restrict__ out_tok,
                                                 int* __restrict__ counts,
                                                 float* __restrict__ embeds,
                                                 float* __restrict__ loss_part) {
    __shared__ float lred[4];
    int w = threadIdx.x >> 6, lane = threadIdx.x & 63;
    int n = blockIdx.x * 4 + w;
    int k = (int)(unsigned int)(keys[n] & 0xFFFFFFFFull);

    size_t xo = (size_t)n * DIM + lane * 4;
    size_t eo = (size_t)k * DIM + lane * 4;
    const float4 xv = *(const float4*)&x[xo];
    const float4 ev = *(const float4*)&e[eo];

    float4 q;  // straight-through: x + (q - x), same rounding as reference
    q.x = xv.x + (ev.x - xv.x);
    q.y = xv.y + (ev.y - xv.y);
    q.z = xv.z + (ev.z - xv.z);
    q.w = xv.w + (ev.w - xv.w);
    *(float4*)&out_q[xo] = q;

    float dx = xv.x - ev.x, dy = xv.y - ev.y, dz = xv.z - ev.z, dw = xv.w - ev.w;
    float ls = dx * dx + dy * dy + dz * dz + dw * dw;
#pragma unroll
    for (int m = 32; m; m >>= 1) ls += __shfl_xor(ls, m, 64);
    if (lane == 0) {
        lred[w] = ls;
        atomicAdd(&counts[k], 1);
        out_tok[n] = (float)k;
    }

    atomicAdd(&embeds[eo + 0], xv.x);
    atomicAdd(&embeds[eo + 1], xv.y);
    atomicAdd(&embeds[eo + 2], xv.z);
    atomicAdd(&embeds[eo + 3], xv.w);

    __syncthreads();
    if (threadIdx.x == 0)
        loss_part[blockIdx.x] = lred[0] + lred[1] + lred[2] + lred[3];
}

__global__ __launch_bounds__(1024) void k_stats(const float* __restrict__ cs,
                                                const int* __restrict__ counts,
                                                const float* __restrict__ loss_part,
                                                float* __restrict__ out_loss,
                                                float* __restrict__ out_ncs,
                                                float* __restrict__ ws_total) {
    __shared__ float red[1024];
    int t = threadIdx.x;

    float ls = 0.0f;
    for (int i = t; i < 8192; i += 1024) ls += loss_part[i];
    red[t] = ls;
    __syncthreads();
    for (int s = 512; s; s >>= 1) {
        if (t < s) red[t] += red[t + s];
        __syncthreads();
    }
    if (t == 0) out_loss[0] = red[0] / 8388608.0f;
    __syncthreads();

    float ncs = cs[t] * DECAYF + (1.0f - DECAYF) * (float)counts[t];
    out_ncs[t] = ncs;
    red[t] = ncs;
    __syncthreads();
    for (int s = 512; s; s >>= 1) {
        if (t < s) red[t] += red[t + s];
        __syncthreads();
    }
    if (t == 0) ws_total[0] = red[0];
}

__global__ __launch_bounds__(64) void k_final(const float* __restrict__ avg,
                                              const float* __restrict__ embeds,
                                              const float* __restrict__ out_ncs,
                                              const float* __restrict__ ws_total,
                                              float* __restrict__ out_emb,
                                              float* __restrict__ out_avg) {
    int k = blockIdx.x, lane = threadIdx.x;
    float total = ws_total[0];
    float ncs = out_ncs[k];
    float normalized = (ncs + EPSF) / (total + (float)KCODES * EPSF) * total;

    size_t o = (size_t)k * DIM + lane * 4;
    float4 av = *(const float4*)&avg[o];
    float4 em = *(const float4*)&embeds[o];
    float4 na, ne;
    na.x = av.x * DECAYF + (1.0f - DECAYF) * em.x;
    na.y = av.y * DECAYF + (1.0f - DECAYF) * em.y;
    na.z = av.z * DECAYF + (1.0f - DECAYF) * em.z;
    na.w = av.w * DECAYF + (1.0f - DECAYF) * em.w;
    ne.x = na.x / normalized;
    ne.y = na.y / normalized;
    ne.z = na.z / normalized;
    ne.w = na.w / normalized;
    *(float4*)&out_avg[o] = na;
    *(float4*)&out_emb[o] = ne;
}

extern "C" void kernel_launch(void* const* d_in, const int* in_sizes, int n_in,
                              void* d_out, int out_size, void* d_ws, size_t ws_size,
                              hipStream_t stream) {
    const float* x   = (const float*)d_in[0];  // inputs [128,16,16,256]
    const float* emb = (const float*)d_in[1];  // embedding [1024,256]
    const float* cs  = (const float*)d_in[2];  // cluster_size [1024]
    const float* avg = (const float*)d_in[3];  // embedding_avg [1024,256]

    float* out      = (float*)d_out;
    float* out_q    = out;
    float* out_tok  = out + 8388608;
    float* out_loss = out + 8421376;
    float* out_emb  = out + 8421377;
    float* out_ncs  = out + 8683521;
    float* out_avg  = out + 8684545;

    char* ws         = (char*)d_ws;
    unsigned long long* keys = (unsigned long long*)ws;
    int* counts      = (int*)(ws + 262144);
    float* embeds    = (float*)(ws + 266240);
    float* loss_part = (float*)(ws + 1314816);
    float* enorm     = (float*)(ws + 1347584);
    float* ws_total  = (float*)(ws + 1351680);

    // keys -> all-ones (max u64); counts+embeds -> 0
    hipMemsetAsync(ws, 0xFF, 262144, stream);
    hipMemsetAsync(ws + 262144, 0, 4096 + 1048576, stream);

    k_enorm<<<KCODES / 4, 256, 0, stream>>>(emb, enorm);
    k_dist<<<NROWS / 64 * 2, 256, 0, stream>>>(x, emb, enorm, keys);
    k_scatter<<<NROWS / 4, 256, 0, stream>>>(x, emb, keys, out_q, out_tok,
                                             counts, embeds, loss_part);
    k_stats<<<1, 1024, 0, stream>>>(cs, counts, loss_part, out_loss, out_ncs,
                                    ws_total);
    k_final<<<KCODES, 64, 0, stream>>>(avg, embeds, out_ncs, ws_total, out_emb,
                                       out_avg);
}

// Round 6
// 505.197 us; speedup vs baseline: 1.5479x; 1.5479x over previous
//
#include <hip/hip_runtime.h>

#define NROWS 32768
#define DIM 256
#define KCODES 1024
#define DECAYF 0.99f
#define EPSF 1e-5f

typedef float f32x4 __attribute__((ext_vector_type(4)));
typedef short short8 __attribute__((ext_vector_type(8)));

// ---------------- workspace layout (bytes), ~53.3 MB ----------------
// xh: 0          xm: 16777216   xl: 33554432          (each 16 MB)
// eh: 50331648   em: 50855936   el: 51380224          (each 512 KB)
// keys u64[32768]:   51904512   (256 KB)
// counts int[1024]:  52166656
// embeds f32[256K]:  52170752   (1 MB)
// loss_part[8192]:   53219328
// enorm[1024]:       53252096
// ws_total:          53256192

// ---------------- output layout (floats) ----------------
// quantized_st [0,8388608) | token_ids [8388608,8421376) | loss [8421376]
// new_embedding [8421377,8683521) | new_cluster_size [8683521,8684545)
// new_embedding_avg [8684545,8946689)

__device__ inline unsigned short f2bf(float f) {
    unsigned u = __float_as_uint(f);
    return (unsigned short)((u + 0x7FFFu + ((u >> 16) & 1u)) >> 16);
}
__device__ inline float bf2f(unsigned short h) {
    return __uint_as_float(((unsigned)h) << 16);
}

// split fp32 -> 3 bf16 planes (h+m+l represents x to ~24 sig bits)
__global__ __launch_bounds__(256) void k_split(const float* __restrict__ x,
                                               unsigned short* __restrict__ ph,
                                               unsigned short* __restrict__ pm,
                                               unsigned short* __restrict__ pl) {
    int i = blockIdx.x * 256 + threadIdx.x;  // group of 8 floats
    const float4* xp = (const float4*)x;
    float4 a = xp[i * 2], b = xp[i * 2 + 1];
    float v[8] = {a.x, a.y, a.z, a.w, b.x, b.y, b.z, b.w};
    short8 H, M, L;
#pragma unroll
    for (int u = 0; u < 8; ++u) {
        unsigned short h = f2bf(v[u]);
        float r1 = v[u] - bf2f(h);
        unsigned short m = f2bf(r1);
        float r2 = r1 - bf2f(m);
        unsigned short l = f2bf(r2);
        H[u] = (short)h; M[u] = (short)m; L[u] = (short)l;
    }
    *(short8*)&ph[(size_t)i * 8] = H;
    *(short8*)&pm[(size_t)i * 8] = M;
    *(short8*)&pl[(size_t)i * 8] = L;
}

__global__ __launch_bounds__(256) void k_enorm(const float* __restrict__ e,
                                               float* __restrict__ enorm) {
    int w = threadIdx.x >> 6, lane = threadIdx.x & 63;
    int c = blockIdx.x * 4 + w;
    const float4 v = *(const float4*)&e[(size_t)c * DIM + lane * 4];
    float s = v.x * v.x + v.y * v.y + v.z * v.z + v.w * v.w;
#pragma unroll
    for (int m = 32; m; m >>= 1) s += __shfl_xor(s, m, 64);
    if (lane == 0) enorm[c] = s;
}

// MFMA distance + fused argmin. 6-term split-bf16 emulated-fp32 GEMM.
// Block: 256 thr = 4 waves (2x2 wave grid, 64x64 per wave), tile 128x128.
// K-loop: 6 terms x 4 steps of BK=64. LDS: fragment-ordered subtiles
// (16 rows/cols x 32 k, 1KB each, read/written at lane*16B: conflict-free).
__global__ __launch_bounds__(256) void k_distm(
    const unsigned short* __restrict__ xh, const unsigned short* __restrict__ xm,
    const unsigned short* __restrict__ xl, const unsigned short* __restrict__ eh,
    const unsigned short* __restrict__ em, const unsigned short* __restrict__ el,
    const float* __restrict__ enorm, unsigned long long* __restrict__ keys) {
    __shared__ unsigned short Als[8192];  // 16 subtiles x 512 bf16 = 16KB
    __shared__ unsigned short Bls[8192];

    const int t = threadIdx.x;
    const int l = t & 63, w = t >> 6;
    const int wr = w >> 1, wc = w & 1;
    // swizzle: 8 col-siblings of a row-panel share (bid%8) -> same XCD
    const int bid = blockIdx.x;
    const int brow = (bid & 255) * 128;
    const int bcol = (bid >> 8) * 128;

    float en[4];
    int cidx[4];
#pragma unroll
    for (int j = 0; j < 4; ++j) {
        cidx[j] = bcol + wc * 64 + j * 16 + (l & 15);
        en[j] = enorm[cidx[j]];
    }

    f32x4 acc[4][4] = {};

    const unsigned short* Ap[6] = {xh, xh, xm, xh, xl, xm};
    const unsigned short* Bp[6] = {eh, em, eh, el, eh, em};

#pragma unroll
    for (int term = 0; term < 6; ++term) {
        const unsigned short* pa = Ap[term];
        const unsigned short* pb = Bp[term];
        for (int t4 = 0; t4 < 4; ++t4) {
            int k0 = t4 * 64;
            __syncthreads();
            if (w < 2) {  // waves 0,1 stage A rows
#pragma unroll
                for (int u = 0; u < 4; ++u) {
                    int rg = w * 4 + u;
                    int row = brow + rg * 16 + (l & 15);
#pragma unroll
                    for (int kg = 0; kg < 2; ++kg) {
                        int k = k0 + kg * 32 + (l >> 4) * 8;
                        f32x4 v = *(const f32x4*)&pa[(size_t)row * 256 + k];
                        *(f32x4*)&Als[(rg * 2 + kg) * 512 + l * 8] = v;
                    }
                }
            } else {  // waves 2,3 stage B codes
#pragma unroll
                for (int u = 0; u < 4; ++u) {
                    int cg = (w - 2) * 4 + u;
                    int col = bcol + cg * 16 + (l & 15);
#pragma unroll
                    for (int kg = 0; kg < 2; ++kg) {
                        int k = k0 + kg * 32 + (l >> 4) * 8;
                        f32x4 v = *(const f32x4*)&pb[(size_t)col * 256 + k];
                        *(f32x4*)&Bls[(cg * 2 + kg) * 512 + l * 8] = v;
                    }
                }
            }
            __syncthreads();
#pragma unroll
            for (int kg = 0; kg < 2; ++kg) {
                short8 af[4], bf[4];
#pragma unroll
                for (int i = 0; i < 4; ++i)
                    af[i] = *(const short8*)&Als[((wr * 4 + i) * 2 + kg) * 512 + l * 8];
#pragma unroll
                for (int j = 0; j < 4; ++j)
                    bf[j] = *(const short8*)&Bls[((wc * 4 + j) * 2 + kg) * 512 + l * 8];
#pragma unroll
                for (int i = 0; i < 4; ++i)
#pragma unroll
                    for (int j = 0; j < 4; ++j)
                        acc[i][j] = __builtin_amdgcn_mfma_f32_16x16x32_bf16(
                            af[i], bf[j], acc[i][j], 0, 0, 0);
            }
        }
    }

    // epilogue: dist = ||e||^2 - 2 x.e ; per-row argmin over wave's 64 codes
    // C layout: col = lane&15 (code), row = (lane>>4)*4 + reg (x-row)
#pragma unroll
    for (int i = 0; i < 4; ++i) {
#pragma unroll
        for (int r = 0; r < 4; ++r) {
            float best = 3.0e38f;
            int bi = 0x7FFFFFFF;
#pragma unroll
            for (int j = 0; j < 4; ++j) {
                float d = en[j] - 2.0f * acc[i][j][r];
                if (d < best || (d == best && cidx[j] < bi)) { best = d; bi = cidx[j]; }
            }
#pragma unroll
            for (int m = 1; m < 16; m <<= 1) {
                float d2 = __shfl_xor(best, m, 64);
                int b2 = __shfl_xor(bi, m, 64);
                if (d2 < best || (d2 == best && b2 < bi)) { best = d2; bi = b2; }
            }
            if ((l & 15) == 0) {
                int grow = brow + wr * 64 + i * 16 + (l >> 4) * 4 + r;
                unsigned int fb = __float_as_uint(best);
                unsigned int key32 = (fb & 0x80000000u) ? ~fb : (fb | 0x80000000u);
                atomicMin(&keys[grow],
                          ((unsigned long long)key32 << 32) | (unsigned)bi);
            }
        }
    }
}

// gather quantized rows, straight-through output, loss partials, EMA scatter
__global__ __launch_bounds__(256) void k_scatter(const float* __restrict__ x,
                                                 const float* __restrict__ e,
                                                 const unsigned long long* __restrict__ keys,
                                                 float* __restrict__ out_q,
                                                 float* __restrict__ out_tok,
                                                 int* __restrict__ counts,
                                                 float* __restrict__ embeds,
                                                 float* __restrict__ loss_part) {
    __shared__ float lred[4];
    int w = threadIdx.x >> 6, lane = threadIdx.x & 63;
    int n = blockIdx.x * 4 + w;
    int k = (int)(unsigned int)(keys[n] & 0xFFFFFFFFull);

    size_t xo = (size_t)n * DIM + lane * 4;
    size_t eo = (size_t)k * DIM + lane * 4;
    const float4 xv = *(const float4*)&x[xo];
    const float4 ev = *(const float4*)&e[eo];

    float4 q;
    q.x = xv.x + (ev.x - xv.x);
    q.y = xv.y + (ev.y - xv.y);
    q.z = xv.z + (ev.z - xv.z);
    q.w = xv.w + (ev.w - xv.w);
    *(float4*)&out_q[xo] = q;

    float dx = xv.x - ev.x, dy = xv.y - ev.y, dz = xv.z - ev.z, dw = xv.w - ev.w;
    float ls = dx * dx + dy * dy + dz * dz + dw * dw;
#pragma unroll
    for (int m = 32; m; m >>= 1) ls += __shfl_xor(ls, m, 64);
    if (lane == 0) {
        lred[w] = ls;
        atomicAdd(&counts[k], 1);
        out_tok[n] = (float)k;
    }

    atomicAdd(&embeds[eo + 0], xv.x);
    atomicAdd(&embeds[eo + 1], xv.y);
    atomicAdd(&embeds[eo + 2], xv.z);
    atomicAdd(&embeds[eo + 3], xv.w);

    __syncthreads();
    if (threadIdx.x == 0)
        loss_part[blockIdx.x] = lred[0] + lred[1] + lred[2] + lred[3];
}

__global__ __launch_bounds__(1024) void k_stats(const float* __restrict__ cs,
                                                const int* __restrict__ counts,
                                                const float* __restrict__ loss_part,
                                                float* __restrict__ out_loss,
                                                float* __restrict__ out_ncs,
                                                float* __restrict__ ws_total) {
    __shared__ float red[1024];
    int t = threadIdx.x;

    float ls = 0.0f;
    for (int i = t; i < 8192; i += 1024) ls += loss_part[i];
    red[t] = ls;
    __syncthreads();
    for (int s = 512; s; s >>= 1) {
        if (t < s) red[t] += red[t + s];
        __syncthreads();
    }
    if (t == 0) out_loss[0] = red[0] / 8388608.0f;
    __syncthreads();

    float ncs = cs[t] * DECAYF + (1.0f - DECAYF) * (float)counts[t];
    out_ncs[t] = ncs;
    red[t] = ncs;
    __syncthreads();
    for (int s = 512; s; s >>= 1) {
        if (t < s) red[t] += red[t + s];
        __syncthreads();
    }
    if (t == 0) ws_total[0] = red[0];
}

__global__ __launch_bounds__(64) void k_final(const float* __restrict__ avg,
                                              const float* __restrict__ embeds,
                                              const float* __restrict__ out_ncs,
                                              const float* __restrict__ ws_total,
                                              float* __restrict__ out_emb,
                                              float* __restrict__ out_avg) {
    int k = blockIdx.x, lane = threadIdx.x;
    float total = ws_total[0];
    float ncs = out_ncs[k];
    float normalized = (ncs + EPSF) / (total + (float)KCODES * EPSF) * total;

    size_t o = (size_t)k * DIM + lane * 4;
    float4 av = *(const float4*)&avg[o];
    float4 em = *(const float4*)&embeds[o];
    float4 na, ne;
    na.x = av.x * DECAYF + (1.0f - DECAYF) * em.x;
    na.y = av.y * DECAYF + (1.0f - DECAYF) * em.y;
    na.z = av.z * DECAYF + (1.0f - DECAYF) * em.z;
    na.w = av.w * DECAYF + (1.0f - DECAYF) * em.w;
    ne.x = na.x / normalized;
    ne.y = na.y / normalized;
    ne.z = na.z / normalized;
    ne.w = na.w / normalized;
    *(float4*)&out_avg[o] = na;
    *(float4*)&out_emb[o] = ne;
}

extern "C" void kernel_launch(void* const* d_in, const int* in_sizes, int n_in,
                              void* d_out, int out_size, void* d_ws, size_t ws_size,
                              hipStream_t stream) {
    const float* x   = (const float*)d_in[0];
    const float* emb = (const float*)d_in[1];
    const float* cs  = (const float*)d_in[2];
    const float* avg = (const float*)d_in[3];

    float* out      = (float*)d_out;
    float* out_q    = out;
    float* out_tok  = out + 8388608;
    float* out_loss = out + 8421376;
    float* out_emb  = out + 8421377;
    float* out_ncs  = out + 8683521;
    float* out_avg  = out + 8684545;

    char* ws = (char*)d_ws;
    unsigned short* xh = (unsigned short*)(ws + 0);
    unsigned short* xm = (unsigned short*)(ws + 16777216);
    unsigned short* xl = (unsigned short*)(ws + 33554432);
    unsigned short* eh = (unsigned short*)(ws + 50331648);
    unsigned short* em = (unsigned short*)(ws + 50855936);
    unsigned short* el = (unsigned short*)(ws + 51380224);
    unsigned long long* keys = (unsigned long long*)(ws + 51904512);
    int* counts      = (int*)(ws + 52166656);
    float* embeds    = (float*)(ws + 52170752);
    float* loss_part = (float*)(ws + 53219328);
    float* enorm     = (float*)(ws + 53252096);
    float* ws_total  = (float*)(ws + 53256192);

    hipMemsetAsync(ws + 51904512, 0xFF, 262144, stream);              // keys
    hipMemsetAsync(ws + 52166656, 0, 4096 + 1048576, stream);         // counts+embeds

    k_split<<<4096, 256, 0, stream>>>(x, xh, xm, xl);
    k_split<<<128, 256, 0, stream>>>(emb, eh, em, el);
    k_enorm<<<KCODES / 4, 256, 0, stream>>>(emb, enorm);
    k_distm<<<2048, 256, 0, stream>>>(xh, xm, xl, eh, em, el, enorm, keys);
    k_scatter<<<NROWS / 4, 256, 0, stream>>>(x, emb, keys, out_q, out_tok,
                                             counts, embeds, loss_part);
    k_stats<<<1, 1024, 0, stream>>>(cs, counts, loss_part, out_loss, out_ncs,
                                    ws_total);
    k_final<<<KCODES, 64, 0, stream>>>(avg, embeds, out_ncs, ws_total, out_emb,
                                       out_avg);
}

// Round 7
// 483.815 us; speedup vs baseline: 1.6164x; 1.0442x over previous
//
#include <hip/hip_runtime.h>

#define NROWS 32768
#define DIM 256
#define KCODES 1024
#define DECAYF 0.99f
#define EPSF 1e-5f

typedef float f32x4 __attribute__((ext_vector_type(4)));
typedef short short8 __attribute__((ext_vector_type(8)));

// ---------------- workspace layout (bytes), ~53.3 MB ----------------
// xh: 0          xm: 16777216   xl: 33554432          (each 16 MB)
// eh: 50331648   em: 50855936   el: 51380224          (each 512 KB)
// keys u64[32768]:   51904512   (256 KB)
// counts int[1024]:  52166656
// embeds f32[256K]:  52170752   (1 MB)
// loss_part[8192]:   53219328
// enorm[1024]:       53252096
// ws_total:          53256192

// ---------------- output layout (floats) ----------------
// quantized_st [0,8388608) | token_ids [8388608,8421376) | loss [8421376]
// new_embedding [8421377,8683521) | new_cluster_size [8683521,8684545)
// new_embedding_avg [8684545,8946689)

__device__ inline unsigned short f2bf(float f) {
    unsigned u = __float_as_uint(f);
    return (unsigned short)((u + 0x7FFFu + ((u >> 16) & 1u)) >> 16);
}
__device__ inline float bf2f(unsigned short h) {
    return __uint_as_float(((unsigned)h) << 16);
}

// async global->LDS, 16B per lane; LDS dest = wave-uniform base + lane*16
__device__ __forceinline__ void gload_lds16(const void* g, void* l) {
    __builtin_amdgcn_global_load_lds(
        (const __attribute__((address_space(1))) unsigned int*)g,
        (__attribute__((address_space(3))) unsigned int*)l, 16, 0, 0);
}

// split fp32 -> 3 bf16 planes (h+m+l represents x to ~24 sig bits)
__global__ __launch_bounds__(256) void k_split(const float* __restrict__ x,
                                               unsigned short* __restrict__ ph,
                                               unsigned short* __restrict__ pm,
                                               unsigned short* __restrict__ pl) {
    int i = blockIdx.x * 256 + threadIdx.x;  // group of 8 floats
    const float4* xp = (const float4*)x;
    float4 a = xp[i * 2], b = xp[i * 2 + 1];
    float v[8] = {a.x, a.y, a.z, a.w, b.x, b.y, b.z, b.w};
    short8 H, M, L;
#pragma unroll
    for (int u = 0; u < 8; ++u) {
        unsigned short h = f2bf(v[u]);
        float r1 = v[u] - bf2f(h);
        unsigned short m = f2bf(r1);
        float r2 = r1 - bf2f(m);
        unsigned short l = f2bf(r2);
        H[u] = (short)h; M[u] = (short)m; L[u] = (short)l;
    }
    *(short8*)&ph[(size_t)i * 8] = H;
    *(short8*)&pm[(size_t)i * 8] = M;
    *(short8*)&pl[(size_t)i * 8] = L;
}

__global__ __launch_bounds__(256) void k_enorm(const float* __restrict__ e,
                                               float* __restrict__ enorm) {
    int w = threadIdx.x >> 6, lane = threadIdx.x & 63;
    int c = blockIdx.x * 4 + w;
    const float4 v = *(const float4*)&e[(size_t)c * DIM + lane * 4];
    float s = v.x * v.x + v.y * v.y + v.z * v.z + v.w * v.w;
#pragma unroll
    for (int m = 32; m; m >>= 1) s += __shfl_xor(s, m, 64);
    if (lane == 0) enorm[c] = s;
}

// MFMA distance + fused argmin. 6-term split-bf16 emulated-fp32 GEMM.
// Block: 256 thr = 4 waves (2x2 wave grid, 64x64 per wave), tile 128x128.
// Staging via global_load_lds width=16 (no VGPR round-trip).
// XCD-aware bid remap: each XCD gets a contiguous logical chunk in which
// the 8 col-siblings of a row-panel are dispatch-adjacent -> A-panel L2 reuse.
__global__ __launch_bounds__(256) void k_distm(
    const unsigned short* __restrict__ xh, const unsigned short* __restrict__ xm,
    const unsigned short* __restrict__ xl, const unsigned short* __restrict__ eh,
    const unsigned short* __restrict__ em, const unsigned short* __restrict__ el,
    const float* __restrict__ enorm, unsigned long long* __restrict__ keys) {
    __shared__ unsigned short Als[8192];  // 16 subtiles x 512 bf16 = 16KB
    __shared__ unsigned short Bls[8192];

    const int t = threadIdx.x;
    const int l = t & 63, w = t >> 6;
    const int wr = w >> 1, wc = w & 1;
    const int b = blockIdx.x;
    const int logical = (b & 7) * 256 + (b >> 3);  // bijective: 2048 % 8 == 0
    const int brow = (logical >> 3) * 128;
    const int bcol = (logical & 7) * 128;

    float en[4];
    int cidx[4];
#pragma unroll
    for (int j = 0; j < 4; ++j) {
        cidx[j] = bcol + wc * 64 + j * 16 + (l & 15);
        en[j] = enorm[cidx[j]];
    }

    f32x4 acc[4][4] = {};

    const unsigned short* Ap[6] = {xh, xh, xm, xh, xl, xm};
    const unsigned short* Bp[6] = {eh, em, eh, el, eh, em};

    // per-lane source offsets within a subtile column group
    const int rlane = l & 15;          // row/col within 16-group
    const int klane = (l >> 4) * 8;    // k offset within 32-k subtile

#pragma unroll
    for (int term = 0; term < 6; ++term) {
        const unsigned short* pa = Ap[term];
        const unsigned short* pb = Bp[term];
        for (int t4 = 0; t4 < 4; ++t4) {
            int k0 = t4 * 64;
            __syncthreads();
            // wave w stages 8 subtiles: w=0,1 -> A halves; w=2,3 -> B halves
            {
                const unsigned short* p = (w < 2) ? pa : pb;
                int base = (w < 2) ? brow : bcol;
                unsigned short* lbase = (w < 2) ? Als : Bls;
                int half = w & 1;
#pragma unroll
                for (int u = 0; u < 4; ++u) {
                    int sg = half * 4 + u;            // rg/cg 0..7
                    int rc = base + sg * 16 + rlane;
#pragma unroll
                    for (int kg = 0; kg < 2; ++kg) {
                        int k = k0 + kg * 32 + klane;
                        gload_lds16(&p[(size_t)rc * 256 + k],
                                    &lbase[(sg * 2 + kg) * 512]);
                    }
                }
            }
            __syncthreads();
#pragma unroll
            for (int kg = 0; kg < 2; ++kg) {
                short8 af[4], bf[4];
#pragma unroll
                for (int i = 0; i < 4; ++i)
                    af[i] = *(const short8*)&Als[((wr * 4 + i) * 2 + kg) * 512 + l * 8];
#pragma unroll
                for (int j = 0; j < 4; ++j)
                    bf[j] = *(const short8*)&Bls[((wc * 4 + j) * 2 + kg) * 512 + l * 8];
#pragma unroll
                for (int i = 0; i < 4; ++i)
#pragma unroll
                    for (int j = 0; j < 4; ++j)
                        acc[i][j] = __builtin_amdgcn_mfma_f32_16x16x32_bf16(
                            af[i], bf[j], acc[i][j], 0, 0, 0);
            }
        }
    }

    // epilogue: dist = ||e||^2 - 2 x.e ; per-row argmin over wave's 64 codes
    // C layout: col = lane&15 (code), row = (lane>>4)*4 + reg (x-row)
#pragma unroll
    for (int i = 0; i < 4; ++i) {
#pragma unroll
        for (int r = 0; r < 4; ++r) {
            float best = 3.0e38f;
            int bi = 0x7FFFFFFF;
#pragma unroll
            for (int j = 0; j < 4; ++j) {
                float d = en[j] - 2.0f * acc[i][j][r];
                if (d < best || (d == best && cidx[j] < bi)) { best = d; bi = cidx[j]; }
            }
#pragma unroll
            for (int m = 1; m < 16; m <<= 1) {
                float d2 = __shfl_xor(best, m, 64);
                int b2 = __shfl_xor(bi, m, 64);
                if (d2 < best || (d2 == best && b2 < bi)) { best = d2; bi = b2; }
            }
            if ((l & 15) == 0) {
                int grow = brow + wr * 64 + i * 16 + (l >> 4) * 4 + r;
                unsigned int fb = __float_as_uint(best);
                unsigned int key32 = (fb & 0x80000000u) ? ~fb : (fb | 0x80000000u);
                atomicMin(&keys[grow],
                          ((unsigned long long)key32 << 32) | (unsigned)bi);
            }
        }
    }
}

// gather quantized rows, straight-through output, loss partials, EMA scatter
__global__ __launch_bounds__(256) void k_scatter(const float* __restrict__ x,
                                                 const float* __restrict__ e,
                                                 const unsigned long long* __restrict__ keys,
                                                 float* __restrict__ out_q,
                                                 float* __restrict__ out_tok,
                                                 int* __restrict__ counts,
                                                 float* __restrict__ embeds,
                                                 float* __restrict__ loss_part) {
    __shared__ float lred[4];
    int w = threadIdx.x >> 6, lane = threadIdx.x & 63;
    int n = blockIdx.x * 4 + w;
    int k = (int)(unsigned int)(keys[n] & 0xFFFFFFFFull);

    size_t xo = (size_t)n * DIM + lane * 4;
    size_t eo = (size_t)k * DIM + lane * 4;
    const float4 xv = *(const float4*)&x[xo];
    const float4 ev = *(const float4*)&e[eo];

    float4 q;
    q.x = xv.x + (ev.x - xv.x);
    q.y = xv.y + (ev.y - xv.y);
    q.z = xv.z + (ev.z - xv.z);
    q.w = xv.w + (ev.w - xv.w);
    *(float4*)&out_q[xo] = q;

    float dx = xv.x - ev.x, dy = xv.y - ev.y, dz = xv.z - ev.z, dw = xv.w - ev.w;
    float ls = dx * dx + dy * dy + dz * dz + dw * dw;
#pragma unroll
    for (int m = 32; m; m >>= 1) ls += __shfl_xor(ls, m, 64);
    if (lane == 0) {
        lred[w] = ls;
        atomicAdd(&counts[k], 1);
        out_tok[n] = (float)k;
    }

    atomicAdd(&embeds[eo + 0], xv.x);
    atomicAdd(&embeds[eo + 1], xv.y);
    atomicAdd(&embeds[eo + 2], xv.z);
    atomicAdd(&embeds[eo + 3], xv.w);

    __syncthreads();
    if (threadIdx.x == 0)
        loss_part[blockIdx.x] = lred[0] + lred[1] + lred[2] + lred[3];
}

__global__ __launch_bounds__(1024) void k_stats(const float* __restrict__ cs,
                                                const int* __restrict__ counts,
                                                const float* __restrict__ loss_part,
                                                float* __restrict__ out_loss,
                                                float* __restrict__ out_ncs,
                                                float* __restrict__ ws_total) {
    __shared__ float red[1024];
    int t = threadIdx.x;

    float ls = 0.0f;
    for (int i = t; i < 8192; i += 1024) ls += loss_part[i];
    red[t] = ls;
    __syncthreads();
    for (int s = 512; s; s >>= 1) {
        if (t < s) red[t] += red[t + s];
        __syncthreads();
    }
    if (t == 0) out_loss[0] = red[0] / 8388608.0f;
    __syncthreads();

    float ncs = cs[t] * DECAYF + (1.0f - DECAYF) * (float)counts[t];
    out_ncs[t] = ncs;
    red[t] = ncs;
    __syncthreads();
    for (int s = 512; s; s >>= 1) {
        if (t < s) red[t] += red[t + s];
        __syncthreads();
    }
    if (t == 0) ws_total[0] = red[0];
}

__global__ __launch_bounds__(64) void k_final(const float* __restrict__ avg,
                                              const float* __restrict__ embeds,
                                              const float* __restrict__ out_ncs,
                                              const float* __restrict__ ws_total,
                                              float* __restrict__ out_emb,
                                              float* __restrict__ out_avg) {
    int k = blockIdx.x, lane = threadIdx.x;
    float total = ws_total[0];
    float ncs = out_ncs[k];
    float normalized = (ncs + EPSF) / (total + (float)KCODES * EPSF) * total;

    size_t o = (size_t)k * DIM + lane * 4;
    float4 av = *(const float4*)&avg[o];
    float4 em = *(const float4*)&embeds[o];
    float4 na, ne;
    na.x = av.x * DECAYF + (1.0f - DECAYF) * em.x;
    na.y = av.y * DECAYF + (1.0f - DECAYF) * em.y;
    na.z = av.z * DECAYF + (1.0f - DECAYF) * em.z;
    na.w = av.w * DECAYF + (1.0f - DECAYF) * em.w;
    ne.x = na.x / normalized;
    ne.y = na.y / normalized;
    ne.z = na.z / normalized;
    ne.w = na.w / normalized;
    *(float4*)&out_avg[o] = na;
    *(float4*)&out_emb[o] = ne;
}

extern "C" void kernel_launch(void* const* d_in, const int* in_sizes, int n_in,
                              void* d_out, int out_size, void* d_ws, size_t ws_size,
                              hipStream_t stream) {
    const float* x   = (const float*)d_in[0];
    const float* emb = (const float*)d_in[1];
    const float* cs  = (const float*)d_in[2];
    const float* avg = (const float*)d_in[3];

    float* out      = (float*)d_out;
    float* out_q    = out;
    float* out_tok  = out + 8388608;
    float* out_loss = out + 8421376;
    float* out_emb  = out + 8421377;
    float* out_ncs  = out + 8683521;
    float* out_avg  = out + 8684545;

    char* ws = (char*)d_ws;
    unsigned short* xh = (unsigned short*)(ws + 0);
    unsigned short* xm = (unsigned short*)(ws + 16777216);
    unsigned short* xl = (unsigned short*)(ws + 33554432);
    unsigned short* eh = (unsigned short*)(ws + 50331648);
    unsigned short* em = (unsigned short*)(ws + 50855936);
    unsigned short* el = (unsigned short*)(ws + 51380224);
    unsigned long long* keys = (unsigned long long*)(ws + 51904512);
    int* counts      = (int*)(ws + 52166656);
    float* embeds    = (float*)(ws + 52170752);
    float* loss_part = (float*)(ws + 53219328);
    float* enorm     = (float*)(ws + 53252096);
    float* ws_total  = (float*)(ws + 53256192);

    hipMemsetAsync(ws + 51904512, 0xFF, 262144, stream);              // keys
    hipMemsetAsync(ws + 52166656, 0, 4096 + 1048576, stream);         // counts+embeds

    k_split<<<4096, 256, 0, stream>>>(x, xh, xm, xl);
    k_split<<<128, 256, 0, stream>>>(emb, eh, em, el);
    k_enorm<<<KCODES / 4, 256, 0, stream>>>(emb, enorm);
    k_distm<<<2048, 256, 0, stream>>>(xh, xm, xl, eh, em, el, enorm, keys);
    k_scatter<<<NROWS / 4, 256, 0, stream>>>(x, emb, keys, out_q, out_tok,
                                             counts, embeds, loss_part);
    k_stats<<<1, 1024, 0, stream>>>(cs, counts, loss_part, out_loss, out_ncs,
                                    ws_total);
    k_final<<<KCODES, 64, 0, stream>>>(avg, embeds, out_ncs, ws_total, out_emb,
                                       out_avg);
}

// Round 8
// 411.807 us; speedup vs baseline: 1.8990x; 1.1749x over previous
//
#include <hip/hip_runtime.h>

#define NROWS 32768
#define DIM 256
#define KCODES 1024
#define DECAYF 0.99f
#define EPSF 1e-5f

typedef float f32x4 __attribute__((ext_vector_type(4)));
typedef short short8 __attribute__((ext_vector_type(8)));

// ---------------- workspace layout (bytes), ~52.3 MB ----------------
// xh: 0          xm: 16777216   xl: 33554432          (each 16 MB)
// eh: 50331648   em: 50855936   el: 51380224          (each 512 KB)
// keys u64[32768]:   51904512   (256 KB)
// counts int[1024]:  52166656
// offsets int[1024]: 52170752
// cursor int[1024]:  52174848
// bucket int[32768]: 52178944   (128 KB)
// loss_part[8192]:   52310016   (32 KB)
// enorm[1024]:       52342784
// ws_total:          52346880

// ---------------- output layout (floats) ----------------
// quantized_st [0,8388608) | token_ids [8388608,8421376) | loss [8421376]
// new_embedding [8421377,8683521) | new_cluster_size [8683521,8684545)
// new_embedding_avg [8684545,8946689)

__device__ inline unsigned short f2bf(float f) {
    unsigned u = __float_as_uint(f);
    return (unsigned short)((u + 0x7FFFu + ((u >> 16) & 1u)) >> 16);
}
__device__ inline float bf2f(unsigned short h) {
    return __uint_as_float(((unsigned)h) << 16);
}

// async global->LDS, 16B per lane; LDS dest = wave-uniform base + lane*16
__device__ __forceinline__ void gload_lds16(const void* g, void* l) {
    __builtin_amdgcn_global_load_lds(
        (const __attribute__((address_space(1))) unsigned int*)g,
        (__attribute__((address_space(3))) unsigned int*)l, 16, 0, 0);
}

// split fp32 -> 3 bf16 planes (h+m+l represents x to ~24 sig bits)
__global__ __launch_bounds__(256) void k_split(const float* __restrict__ x,
                                               unsigned short* __restrict__ ph,
                                               unsigned short* __restrict__ pm,
                                               unsigned short* __restrict__ pl) {
    int i = blockIdx.x * 256 + threadIdx.x;  // group of 8 floats
    const float4* xp = (const float4*)x;
    float4 a = xp[i * 2], b = xp[i * 2 + 1];
    float v[8] = {a.x, a.y, a.z, a.w, b.x, b.y, b.z, b.w};
    short8 H, M, L;
#pragma unroll
    for (int u = 0; u < 8; ++u) {
        unsigned short h = f2bf(v[u]);
        float r1 = v[u] - bf2f(h);
        unsigned short m = f2bf(r1);
        float r2 = r1 - bf2f(m);
        unsigned short l = f2bf(r2);
        H[u] = (short)h; M[u] = (short)m; L[u] = (short)l;
    }
    *(short8*)&ph[(size_t)i * 8] = H;
    *(short8*)&pm[(size_t)i * 8] = M;
    *(short8*)&pl[(size_t)i * 8] = L;
}

__global__ __launch_bounds__(256) void k_enorm(const float* __restrict__ e,
                                               float* __restrict__ enorm) {
    int w = threadIdx.x >> 6, lane = threadIdx.x & 63;
    int c = blockIdx.x * 4 + w;
    const float4 v = *(const float4*)&e[(size_t)c * DIM + lane * 4];
    float s = v.x * v.x + v.y * v.y + v.z * v.z + v.w * v.w;
#pragma unroll
    for (int m = 32; m; m >>= 1) s += __shfl_xor(s, m, 64);
    if (lane == 0) enorm[c] = s;
}

// MFMA distance + fused argmin. 6-term split-bf16 emulated-fp32 GEMM.
// Block: 256 thr = 4 waves (2x2 wave grid, 64x64 per wave), tile 128x128.
// Staging via global_load_lds width=16 (no VGPR round-trip).
__global__ __launch_bounds__(256) void k_distm(
    const unsigned short* __restrict__ xh, const unsigned short* __restrict__ xm,
    const unsigned short* __restrict__ xl, const unsigned short* __restrict__ eh,
    const unsigned short* __restrict__ em, const unsigned short* __restrict__ el,
    const float* __restrict__ enorm, unsigned long long* __restrict__ keys) {
    __shared__ unsigned short Als[8192];  // 16 subtiles x 512 bf16 = 16KB
    __shared__ unsigned short Bls[8192];

    const int t = threadIdx.x;
    const int l = t & 63, w = t >> 6;
    const int wr = w >> 1, wc = w & 1;
    const int b = blockIdx.x;
    const int logical = (b & 7) * 256 + (b >> 3);  // bijective: 2048 % 8 == 0
    const int brow = (logical >> 3) * 128;
    const int bcol = (logical & 7) * 128;

    float en[4];
    int cidx[4];
#pragma unroll
    for (int j = 0; j < 4; ++j) {
        cidx[j] = bcol + wc * 64 + j * 16 + (l & 15);
        en[j] = enorm[cidx[j]];
    }

    f32x4 acc[4][4] = {};

    const unsigned short* Ap[6] = {xh, xh, xm, xh, xl, xm};
    const unsigned short* Bp[6] = {eh, em, eh, el, eh, em};

    const int rlane = l & 15;          // row/col within 16-group
    const int klane = (l >> 4) * 8;    // k offset within 32-k subtile

#pragma unroll
    for (int term = 0; term < 6; ++term) {
        const unsigned short* pa = Ap[term];
        const unsigned short* pb = Bp[term];
        for (int t4 = 0; t4 < 4; ++t4) {
            int k0 = t4 * 64;
            __syncthreads();
            {
                const unsigned short* p = (w < 2) ? pa : pb;
                int base = (w < 2) ? brow : bcol;
                unsigned short* lbase = (w < 2) ? Als : Bls;
                int half = w & 1;
#pragma unroll
                for (int u = 0; u < 4; ++u) {
                    int sg = half * 4 + u;            // rg/cg 0..7
                    int rc = base + sg * 16 + rlane;
#pragma unroll
                    for (int kg = 0; kg < 2; ++kg) {
                        int k = k0 + kg * 32 + klane;
                        gload_lds16(&p[(size_t)rc * 256 + k],
                                    &lbase[(sg * 2 + kg) * 512]);
                    }
                }
            }
            __syncthreads();
#pragma unroll
            for (int kg = 0; kg < 2; ++kg) {
                short8 af[4], bf[4];
#pragma unroll
                for (int i = 0; i < 4; ++i)
                    af[i] = *(const short8*)&Als[((wr * 4 + i) * 2 + kg) * 512 + l * 8];
#pragma unroll
                for (int j = 0; j < 4; ++j)
                    bf[j] = *(const short8*)&Bls[((wc * 4 + j) * 2 + kg) * 512 + l * 8];
#pragma unroll
                for (int i = 0; i < 4; ++i)
#pragma unroll
                    for (int j = 0; j < 4; ++j)
                        acc[i][j] = __builtin_amdgcn_mfma_f32_16x16x32_bf16(
                            af[i], bf[j], acc[i][j], 0, 0, 0);
            }
        }
    }

    // epilogue: dist = ||e||^2 - 2 x.e ; per-row argmin over wave's 64 codes
    // C layout: col = lane&15 (code), row = (lane>>4)*4 + reg (x-row)
#pragma unroll
    for (int i = 0; i < 4; ++i) {
#pragma unroll
        for (int r = 0; r < 4; ++r) {
            float best = 3.0e38f;
            int bi = 0x7FFFFFFF;
#pragma unroll
            for (int j = 0; j < 4; ++j) {
                float d = en[j] - 2.0f * acc[i][j][r];
                if (d < best || (d == best && cidx[j] < bi)) { best = d; bi = cidx[j]; }
            }
#pragma unroll
            for (int m = 1; m < 16; m <<= 1) {
                float d2 = __shfl_xor(best, m, 64);
                int b2 = __shfl_xor(bi, m, 64);
                if (d2 < best || (d2 == best && b2 < bi)) { best = d2; bi = b2; }
            }
            if ((l & 15) == 0) {
                int grow = brow + wr * 64 + i * 16 + (l >> 4) * 4 + r;
                unsigned int fb = __float_as_uint(best);
                unsigned int key32 = (fb & 0x80000000u) ? ~fb : (fb | 0x80000000u);
                atomicMin(&keys[grow],
                          ((unsigned long long)key32 << 32) | (unsigned)bi);
            }
        }
    }
}

// gather quantized rows, straight-through output, loss partials, counts
__global__ __launch_bounds__(256) void k_scatter(const float* __restrict__ x,
                                                 const float* __restrict__ e,
                                                 const unsigned long long* __restrict__ keys,
                                                 float* __restrict__ out_q,
                                                 float* __restrict__ out_tok,
                                                 int* __restrict__ counts,
                                                 float* __restrict__ loss_part) {
    __shared__ float lred[4];
    int w = threadIdx.x >> 6, lane = threadIdx.x & 63;
    int n = blockIdx.x * 4 + w;
    int k = (int)(unsigned int)(keys[n] & 0xFFFFFFFFull);

    size_t xo = (size_t)n * DIM + lane * 4;
    size_t eo = (size_t)k * DIM + lane * 4;
    const float4 xv = *(const float4*)&x[xo];
    const float4 ev = *(const float4*)&e[eo];

    float4 q;
    q.x = xv.x + (ev.x - xv.x);
    q.y = xv.y + (ev.y - xv.y);
    q.z = xv.z + (ev.z - xv.z);
    q.w = xv.w + (ev.w - xv.w);
    *(float4*)&out_q[xo] = q;

    float dx = xv.x - ev.x, dy = xv.y - ev.y, dz = xv.z - ev.z, dw = xv.w - ev.w;
    float ls = dx * dx + dy * dy + dz * dz + dw * dw;
#pragma unroll
    for (int m = 32; m; m >>= 1) ls += __shfl_xor(ls, m, 64);
    if (lane == 0) {
        lred[w] = ls;
        atomicAdd(&counts[k], 1);
        out_tok[n] = (float)k;
    }

    __syncthreads();
    if (threadIdx.x == 0)
        loss_part[blockIdx.x] = lred[0] + lred[1] + lred[2] + lred[3];
}

// exclusive prefix scan of counts -> offsets, cursor (single block)
__global__ __launch_bounds__(1024) void k_prefix(const int* __restrict__ counts,
                                                 int* __restrict__ offsets,
                                                 int* __restrict__ cursor) {
    __shared__ int s[1024];
    int t = threadIdx.x;
    int c = counts[t];
    s[t] = c;
    __syncthreads();
    for (int off = 1; off < 1024; off <<= 1) {
        int v = (t >= off) ? s[t - off] : 0;
        __syncthreads();
        s[t] += v;
        __syncthreads();
    }
    int excl = s[t] - c;
    offsets[t] = excl;
    cursor[t] = excl;
}

// group row ids by code
__global__ __launch_bounds__(256) void k_bucket(const unsigned long long* __restrict__ keys,
                                                int* __restrict__ cursor,
                                                int* __restrict__ bucket) {
    int n = blockIdx.x * 256 + threadIdx.x;
    int k = (int)(unsigned int)(keys[n] & 0xFFFFFFFFull);
    int slot = atomicAdd(&cursor[k], 1);
    bucket[slot] = n;
}

__global__ __launch_bounds__(1024) void k_stats(const float* __restrict__ cs,
                                                const int* __restrict__ counts,
                                                const float* __restrict__ loss_part,
                                                float* __restrict__ out_loss,
                                                float* __restrict__ out_ncs,
                                                float* __restrict__ ws_total) {
    __shared__ float red[1024];
    int t = threadIdx.x;

    float ls = 0.0f;
    for (int i = t; i < 8192; i += 1024) ls += loss_part[i];
    red[t] = ls;
    __syncthreads();
    for (int s = 512; s; s >>= 1) {
        if (t < s) red[t] += red[t + s];
        __syncthreads();
    }
    if (t == 0) out_loss[0] = red[0] / 8388608.0f;
    __syncthreads();

    float ncs = cs[t] * DECAYF + (1.0f - DECAYF) * (float)counts[t];
    out_ncs[t] = ncs;
    red[t] = ncs;
    __syncthreads();
    for (int s = 512; s; s >>= 1) {
        if (t < s) red[t] += red[t + s];
        __syncthreads();
    }
    if (t == 0) ws_total[0] = red[0];
}

// per-code: sum bucketed x rows, then EMA avg + normalized embedding
__global__ __launch_bounds__(256) void k_embfinal(
    const float* __restrict__ x, const int* __restrict__ bucket,
    const int* __restrict__ offsets, const int* __restrict__ counts,
    const float* __restrict__ avg, const float* __restrict__ out_ncs,
    const float* __restrict__ ws_total, float* __restrict__ out_emb,
    float* __restrict__ out_avg) {
    int k = blockIdx.x, d = threadIdx.x;
    int off = offsets[k], cnt = counts[k];

    float sum = 0.0f;
    int i = off;
    for (; i + 4 <= off + cnt; i += 4) {
        int r0 = bucket[i], r1 = bucket[i + 1], r2 = bucket[i + 2], r3 = bucket[i + 3];
        float v0 = x[(size_t)r0 * DIM + d];
        float v1 = x[(size_t)r1 * DIM + d];
        float v2 = x[(size_t)r2 * DIM + d];
        float v3 = x[(size_t)r3 * DIM + d];
        sum += v0; sum += v1; sum += v2; sum += v3;
    }
    for (; i < off + cnt; ++i) sum += x[(size_t)bucket[i] * DIM + d];

    float total = ws_total[0];
    float ncs = out_ncs[k];
    float normalized = (ncs + EPSF) / (total + (float)KCODES * EPSF) * total;

    float na = avg[(size_t)k * DIM + d] * DECAYF + (1.0f - DECAYF) * sum;
    out_avg[(size_t)k * DIM + d] = na;
    out_emb[(size_t)k * DIM + d] = na / normalized;
}

extern "C" void kernel_launch(void* const* d_in, const int* in_sizes, int n_in,
                              void* d_out, int out_size, void* d_ws, size_t ws_size,
                              hipStream_t stream) {
    const float* x   = (const float*)d_in[0];
    const float* emb = (const float*)d_in[1];
    const float* cs  = (const float*)d_in[2];
    const float* avg = (const float*)d_in[3];

    float* out      = (float*)d_out;
    float* out_q    = out;
    float* out_tok  = out + 8388608;
    float* out_loss = out + 8421376;
    float* out_emb  = out + 8421377;
    float* out_ncs  = out + 8683521;
    float* out_avg  = out + 8684545;

    char* ws = (char*)d_ws;
    unsigned short* xh = (unsigned short*)(ws + 0);
    unsigned short* xm = (unsigned short*)(ws + 16777216);
    unsigned short* xl = (unsigned short*)(ws + 33554432);
    unsigned short* eh = (unsigned short*)(ws + 50331648);
    unsigned short* em = (unsigned short*)(ws + 50855936);
    unsigned short* el = (unsigned short*)(ws + 51380224);
    unsigned long long* keys = (unsigned long long*)(ws + 51904512);
    int* counts      = (int*)(ws + 52166656);
    int* offsets     = (int*)(ws + 52170752);
    int* cursor      = (int*)(ws + 52174848);
    int* bucket      = (int*)(ws + 52178944);
    float* loss_part = (float*)(ws + 52310016);
    float* enorm     = (float*)(ws + 52342784);
    float* ws_total  = (float*)(ws + 52346880);

    hipMemsetAsync(ws + 51904512, 0xFF, 262144, stream);  // keys
    hipMemsetAsync(ws + 52166656, 0, 4096, stream);       // counts

    k_split<<<4096, 256, 0, stream>>>(x, xh, xm, xl);
    k_split<<<128, 256, 0, stream>>>(emb, eh, em, el);
    k_enorm<<<KCODES / 4, 256, 0, stream>>>(emb, enorm);
    k_distm<<<2048, 256, 0, stream>>>(xh, xm, xl, eh, em, el, enorm, keys);
    k_scatter<<<NROWS / 4, 256, 0, stream>>>(x, emb, keys, out_q, out_tok,
                                             counts, loss_part);
    k_prefix<<<1, 1024, 0, stream>>>(counts, offsets, cursor);
    k_bucket<<<NROWS / 256, 256, 0, stream>>>(keys, cursor, bucket);
    k_stats<<<1, 1024, 0, stream>>>(cs, counts, loss_part, out_loss, out_ncs,
                                    ws_total);
    k_embfinal<<<KCODES, 256, 0, stream>>>(x, bucket, offsets, counts, avg,
                                           out_ncs, ws_total, out_emb, out_avg);
}

// Round 9
// 398.244 us; speedup vs baseline: 1.9637x; 1.0341x over previous
//
#include <hip/hip_runtime.h>

#define NROWS 32768
#define DIM 256
#define KCODES 1024
#define DECAYF 0.99f
#define EPSF 1e-5f

typedef float f32x4 __attribute__((ext_vector_type(4)));
typedef short short8 __attribute__((ext_vector_type(8)));

// ---------------- workspace layout (bytes), ~52.3 MB ----------------
// xh: 0          xm: 16777216   xl: 33554432          (each 16 MB)
// eh: 50331648   em: 50855936   el: 51380224          (each 512 KB)
// keys u64[32768]:   51904512   (256 KB)
// counts int[1024]:  52166656
// offsets int[1024]: 52170752
// cursor int[1024]:  52174848
// bucket int[32768]: 52178944   (128 KB)
// loss_part[8192]:   52310016   (32 KB)
// enorm[1024]:       52342784
// ws_total:          52346880

// ---------------- output layout (floats) ----------------
// quantized_st [0,8388608) | token_ids [8388608,8421376) | loss [8421376]
// new_embedding [8421377,8683521) | new_cluster_size [8683521,8684545)
// new_embedding_avg [8684545,8946689)

__device__ inline unsigned short f2bf(float f) {
    unsigned u = __float_as_uint(f);
    return (unsigned short)((u + 0x7FFFu + ((u >> 16) & 1u)) >> 16);
}
__device__ inline float bf2f(unsigned short h) {
    return __uint_as_float(((unsigned)h) << 16);
}

// async global->LDS, 16B per lane; LDS dest = wave-uniform base + lane*16
__device__ __forceinline__ void gload_lds16(const void* g, void* l) {
    __builtin_amdgcn_global_load_lds(
        (const __attribute__((address_space(1))) unsigned int*)g,
        (__attribute__((address_space(3))) unsigned int*)l, 16, 0, 0);
}

// fused: split x+emb into 3 bf16 planes, init keys/counts, enorm (verbatim)
__global__ __launch_bounds__(256) void k_split2(
    const float* __restrict__ x, const float* __restrict__ emb,
    unsigned short* __restrict__ xh, unsigned short* __restrict__ xm,
    unsigned short* __restrict__ xl, unsigned short* __restrict__ eh,
    unsigned short* __restrict__ em, unsigned short* __restrict__ el,
    float* __restrict__ enorm, unsigned long long* __restrict__ keys,
    int* __restrict__ counts) {
    int b = blockIdx.x, t = threadIdx.x;
    if (b < 4224) {
        const float* src;
        unsigned short *ph, *pm, *pl;
        int i;
        if (b < 4096) { src = x; ph = xh; pm = xm; pl = xl; i = b * 256 + t; }
        else { src = emb; ph = eh; pm = em; pl = el; i = (b - 4096) * 256 + t; }
        const float4* xp = (const float4*)src;
        float4 a = xp[i * 2], c = xp[i * 2 + 1];
        float v[8] = {a.x, a.y, a.z, a.w, c.x, c.y, c.z, c.w};
        short8 H, M, L;
#pragma unroll
        for (int u = 0; u < 8; ++u) {
            unsigned short h = f2bf(v[u]);
            float r1 = v[u] - bf2f(h);
            unsigned short m = f2bf(r1);
            float r2 = r1 - bf2f(m);
            unsigned short lo = f2bf(r2);
            H[u] = (short)h; M[u] = (short)m; L[u] = (short)lo;
        }
        *(short8*)&ph[(size_t)i * 8] = H;
        *(short8*)&pm[(size_t)i * 8] = M;
        *(short8*)&pl[(size_t)i * 8] = L;
        if (b < 128) keys[b * 256 + t] = 0xFFFFFFFFFFFFFFFFull;
        else if (b < 132) counts[(b - 128) * 256 + t] = 0;
    } else {
        // enorm — body verbatim from the passing k_enorm (same fp32 order)
        int blk = b - 4224;
        int w = t >> 6, lane = t & 63;
        int c = blk * 4 + w;
        const float4 v = *(const float4*)&emb[(size_t)c * DIM + lane * 4];
        float s = v.x * v.x + v.y * v.y + v.z * v.z + v.w * v.w;
#pragma unroll
        for (int m = 32; m; m >>= 1) s += __shfl_xor(s, m, 64);
        if (lane == 0) enorm[c] = s;
    }
}

// MFMA distance + fused argmin. 6-term split-bf16 emulated-fp32 GEMM.
// 2-phase double-buffered: STAGE(s+1) issued before computing step s;
// one vmcnt(0)+barrier per step (in __syncthreads). MFMA order identical
// to the passing round-8 kernel -> bit-identical distances.
__global__ __launch_bounds__(256) void k_distm(
    const unsigned short* __restrict__ xh, const unsigned short* __restrict__ xm,
    const unsigned short* __restrict__ xl, const unsigned short* __restrict__ eh,
    const unsigned short* __restrict__ em, const unsigned short* __restrict__ el,
    const float* __restrict__ enorm, unsigned long long* __restrict__ keys) {
    __shared__ unsigned short Als[2][8192];  // 2 x 16KB
    __shared__ unsigned short Bls[2][8192];

    const int t = threadIdx.x;
    const int l = t & 63, w = t >> 6;
    const int wr = w >> 1, wc = w & 1;
    const int b = blockIdx.x;
    const int logical = (b & 7) * 256 + (b >> 3);  // bijective: 2048 % 8 == 0
    const int brow = (logical >> 3) * 128;
    const int bcol = (logical & 7) * 128;

    float en[4];
    int cidx[4];
#pragma unroll
    for (int j = 0; j < 4; ++j) {
        cidx[j] = bcol + wc * 64 + j * 16 + (l & 15);
        en[j] = enorm[cidx[j]];
    }

    f32x4 acc[4][4] = {};

    const int rlane = l & 15;          // row/col within 16-group
    const int klane = (l >> 4) * 8;    // k offset within 32-k subtile

    // stage step S (S = term*4 + t4) into buffer BB
    auto stage = [&](int S, int BB) {
        int term = S >> 2;
        const unsigned short* p;
        if (w < 2) p = (term == 2 || term == 5) ? xm : (term == 4 ? xl : xh);
        else       p = (term == 1 || term == 5) ? em : (term == 3 ? el : eh);
        int base = (w < 2) ? brow : bcol;
        unsigned short* lb = (w < 2) ? &Als[BB][0] : &Bls[BB][0];
        int k0 = (S & 3) * 64;
        int half = w & 1;
#pragma unroll
        for (int u = 0; u < 4; ++u) {
            int sg = half * 4 + u;
            int rc = base + sg * 16 + rlane;
#pragma unroll
            for (int kg = 0; kg < 2; ++kg) {
                int kk = k0 + kg * 32 + klane;
                gload_lds16(&p[(size_t)rc * 256 + kk], &lb[(sg * 2 + kg) * 512]);
            }
        }
    };

    stage(0, 0);
    __syncthreads();
    int cur = 0;
    for (int s = 0; s < 24; ++s) {
        if (s < 23) stage(s + 1, cur ^ 1);
#pragma unroll
        for (int kg = 0; kg < 2; ++kg) {
            short8 af[4], bf[4];
#pragma unroll
            for (int i = 0; i < 4; ++i)
                af[i] = *(const short8*)&Als[cur][((wr * 4 + i) * 2 + kg) * 512 + l * 8];
#pragma unroll
            for (int j = 0; j < 4; ++j)
                bf[j] = *(const short8*)&Bls[cur][((wc * 4 + j) * 2 + kg) * 512 + l * 8];
#pragma unroll
            for (int i = 0; i < 4; ++i)
#pragma unroll
                for (int j = 0; j < 4; ++j)
                    acc[i][j] = __builtin_amdgcn_mfma_f32_16x16x32_bf16(
                        af[i], bf[j], acc[i][j], 0, 0, 0);
        }
        __syncthreads();  // drains vmcnt(0): next-step stages landed
        cur ^= 1;
    }

    // epilogue: dist = ||e||^2 - 2 x.e ; per-row argmin over wave's 64 codes
    // C layout: col = lane&15 (code), row = (lane>>4)*4 + reg (x-row)
#pragma unroll
    for (int i = 0; i < 4; ++i) {
#pragma unroll
        for (int r = 0; r < 4; ++r) {
            float best = 3.0e38f;
            int bi = 0x7FFFFFFF;
#pragma unroll
            for (int j = 0; j < 4; ++j) {
                float d = en[j] - 2.0f * acc[i][j][r];
                if (d < best || (d == best && cidx[j] < bi)) { best = d; bi = cidx[j]; }
            }
#pragma unroll
            for (int m = 1; m < 16; m <<= 1) {
                float d2 = __shfl_xor(best, m, 64);
                int b2 = __shfl_xor(bi, m, 64);
                if (d2 < best || (d2 == best && b2 < bi)) { best = d2; bi = b2; }
            }
            if ((l & 15) == 0) {
                int grow = brow + wr * 64 + i * 16 + (l >> 4) * 4 + r;
                unsigned int fb = __float_as_uint(best);
                unsigned int key32 = (fb & 0x80000000u) ? ~fb : (fb | 0x80000000u);
                atomicMin(&keys[grow],
                          ((unsigned long long)key32 << 32) | (unsigned)bi);
            }
        }
    }
}

// gather quantized rows, straight-through output, loss partials, counts
__global__ __launch_bounds__(256) void k_scatter(const float* __restrict__ x,
                                                 const float* __restrict__ e,
                                                 const unsigned long long* __restrict__ keys,
                                                 float* __restrict__ out_q,
                                                 float* __restrict__ out_tok,
                                                 int* __restrict__ counts,
                                                 float* __restrict__ loss_part) {
    __shared__ float lred[4];
    int w = threadIdx.x >> 6, lane = threadIdx.x & 63;
    int n = blockIdx.x * 4 + w;
    int k = (int)(unsigned int)(keys[n] & 0xFFFFFFFFull);

    size_t xo = (size_t)n * DIM + lane * 4;
    size_t eo = (size_t)k * DIM + lane * 4;
    const float4 xv = *(const float4*)&x[xo];
    const float4 ev = *(const float4*)&e[eo];

    float4 q;
    q.x = xv.x + (ev.x - xv.x);
    q.y = xv.y + (ev.y - xv.y);
    q.z = xv.z + (ev.z - xv.z);
    q.w = xv.w + (ev.w - xv.w);
    *(float4*)&out_q[xo] = q;

    float dx = xv.x - ev.x, dy = xv.y - ev.y, dz = xv.z - ev.z, dw = xv.w - ev.w;
    float ls = dx * dx + dy * dy + dz * dz + dw * dw;
#pragma unroll
    for (int m = 32; m; m >>= 1) ls += __shfl_xor(ls, m, 64);
    if (lane == 0) {
        lred[w] = ls;
        atomicAdd(&counts[k], 1);
        out_tok[n] = (float)k;
    }

    __syncthreads();
    if (threadIdx.x == 0)
        loss_part[blockIdx.x] = lred[0] + lred[1] + lred[2] + lred[3];
}

// fused: loss reduce + EMA cluster size + total (verbatim k_stats) then
// exclusive prefix scan of counts (verbatim k_prefix)
__global__ __launch_bounds__(1024) void k_mid(const float* __restrict__ cs,
                                              const int* __restrict__ counts,
                                              const float* __restrict__ loss_part,
                                              float* __restrict__ out_loss,
                                              float* __restrict__ out_ncs,
                                              float* __restrict__ ws_total,
                                              int* __restrict__ offsets,
                                              int* __restrict__ cursor) {
    __shared__ float red[1024];
    __shared__ int si[1024];
    int t = threadIdx.x;

    float ls = 0.0f;
    for (int i = t; i < 8192; i += 1024) ls += loss_part[i];
    red[t] = ls;
    __syncthreads();
    for (int s = 512; s; s >>= 1) {
        if (t < s) red[t] += red[t + s];
        __syncthreads();
    }
    if (t == 0) out_loss[0] = red[0] / 8388608.0f;
    __syncthreads();

    float ncs = cs[t] * DECAYF + (1.0f - DECAYF) * (float)counts[t];
    out_ncs[t] = ncs;
    red[t] = ncs;
    __syncthreads();
    for (int s = 512; s; s >>= 1) {
        if (t < s) red[t] += red[t + s];
        __syncthreads();
    }
    if (t == 0) ws_total[0] = red[0];
    __syncthreads();

    int c = counts[t];
    si[t] = c;
    __syncthreads();
    for (int off = 1; off < 1024; off <<= 1) {
        int v = (t >= off) ? si[t - off] : 0;
        __syncthreads();
        si[t] += v;
        __syncthreads();
    }
    int excl = si[t] - c;
    offsets[t] = excl;
    cursor[t] = excl;
}

// group row ids by code
__global__ __launch_bounds__(256) void k_bucket(const unsigned long long* __restrict__ keys,
                                                int* __restrict__ cursor,
                                                int* __restrict__ bucket) {
    int n = blockIdx.x * 256 + threadIdx.x;
    int k = (int)(unsigned int)(keys[n] & 0xFFFFFFFFull);
    int slot = atomicAdd(&cursor[k], 1);
    bucket[slot] = n;
}

// per-code: sum bucketed x rows, then EMA avg + normalized embedding
__global__ __launch_bounds__(256) void k_embfinal(
    const float* __restrict__ x, const int* __restrict__ bucket,
    const int* __restrict__ offsets, const int* __restrict__ counts,
    const float* __restrict__ avg, const float* __restrict__ out_ncs,
    const float* __restrict__ ws_total, float* __restrict__ out_emb,
    float* __restrict__ out_avg) {
    int k = blockIdx.x, d = threadIdx.x;
    int off = offsets[k], cnt = counts[k];

    float sum = 0.0f;
    int i = off;
    for (; i + 4 <= off + cnt; i += 4) {
        int r0 = bucket[i], r1 = bucket[i + 1], r2 = bucket[i + 2], r3 = bucket[i + 3];
        float v0 = x[(size_t)r0 * DIM + d];
        float v1 = x[(size_t)r1 * DIM + d];
        float v2 = x[(size_t)r2 * DIM + d];
        float v3 = x[(size_t)r3 * DIM + d];
        sum += v0; sum += v1; sum += v2; sum += v3;
    }
    for (; i < off + cnt; ++i) sum += x[(size_t)bucket[i] * DIM + d];

    float total = ws_total[0];
    float ncs = out_ncs[k];
    float normalized = (ncs + EPSF) / (total + (float)KCODES * EPSF) * total;

    float na = avg[(size_t)k * DIM + d] * DECAYF + (1.0f - DECAYF) * sum;
    out_avg[(size_t)k * DIM + d] = na;
    out_emb[(size_t)k * DIM + d] = na / normalized;
}

extern "C" void kernel_launch(void* const* d_in, const int* in_sizes, int n_in,
                              void* d_out, int out_size, void* d_ws, size_t ws_size,
                              hipStream_t stream) {
    const float* x   = (const float*)d_in[0];
    const float* emb = (const float*)d_in[1];
    const float* cs  = (const float*)d_in[2];
    const float* avg = (const float*)d_in[3];

    float* out      = (float*)d_out;
    float* out_q    = out;
    float* out_tok  = out + 8388608;
    float* out_loss = out + 8421376;
    float* out_emb  = out + 8421377;
    float* out_ncs  = out + 8683521;
    float* out_avg  = out + 8684545;

    char* ws = (char*)d_ws;
    unsigned short* xh = (unsigned short*)(ws + 0);
    unsigned short* xm = (unsigned short*)(ws + 16777216);
    unsigned short* xl = (unsigned short*)(ws + 33554432);
    unsigned short* eh = (unsigned short*)(ws + 50331648);
    unsigned short* em = (unsigned short*)(ws + 50855936);
    unsigned short* el = (unsigned short*)(ws + 51380224);
    unsigned long long* keys = (unsigned long long*)(ws + 51904512);
    int* counts      = (int*)(ws + 52166656);
    int* offsets     = (int*)(ws + 52170752);
    int* cursor      = (int*)(ws + 52174848);
    int* bucket      = (int*)(ws + 52178944);
    float* loss_part = (float*)(ws + 52310016);
    float* enorm     = (float*)(ws + 52342784);
    float* ws_total  = (float*)(ws + 52346880);

    k_split2<<<4480, 256, 0, stream>>>(x, emb, xh, xm, xl, eh, em, el,
                                       enorm, keys, counts);
    k_distm<<<2048, 256, 0, stream>>>(xh, xm, xl, eh, em, el, enorm, keys);
    k_scatter<<<NROWS / 4, 256, 0, stream>>>(x, emb, keys, out_q, out_tok,
                                             counts, loss_part);
    k_mid<<<1, 1024, 0, stream>>>(cs, counts, loss_part, out_loss, out_ncs,
                                  ws_total, offsets, cursor);
    k_bucket<<<NROWS / 256, 256, 0, stream>>>(keys, cursor, bucket);
    k_embfinal<<<KCODES, 256, 0, stream>>>(x, bucket, offsets, counts, avg,
                                           out_ncs, ws_total, out_emb, out_avg);
}

// Round 10
// 318.828 us; speedup vs baseline: 2.4528x; 1.2491x over previous
//
#include <hip/hip_runtime.h>

#define NROWS 32768
#define DIM 256
#define KCODES 1024
#define DECAYF 0.99f
#define EPSF 1e-5f

typedef float f32x4 __attribute__((ext_vector_type(4)));
typedef short short8 __attribute__((ext_vector_type(8)));

// ---------------- workspace layout (bytes), ~52.3 MB ----------------
// xh: 0          xm: 16777216   xl: 33554432          (each 16 MB)
// eh: 50331648   em: 50855936   el: 51380224          (each 512 KB)
// keys u64[32768]:   51904512   (256 KB)
// counts int[1024]:  52166656
// offsets int[1024]: 52170752
// cursor int[1024]:  52174848
// bucket int[32768]: 52178944   (128 KB)
// loss_part[8192]:   52310016   (32 KB)
// enorm[1024]:       52342784
// ws_total:          52346880

__device__ inline unsigned short f2bf(float f) {
    unsigned u = __float_as_uint(f);
    return (unsigned short)((u + 0x7FFFu + ((u >> 16) & 1u)) >> 16);
}
__device__ inline float bf2f(unsigned short h) {
    return __uint_as_float(((unsigned)h) << 16);
}

// async global->LDS, 16B per lane; LDS dest = wave-uniform base + lane*16
__device__ __forceinline__ void gload_lds16(const void* g, void* l) {
    __builtin_amdgcn_global_load_lds(
        (const __attribute__((address_space(1))) unsigned int*)g,
        (__attribute__((address_space(3))) unsigned int*)l, 16, 0, 0);
}

// fused: split x+emb into 3 bf16 planes, init keys/counts, enorm (verbatim)
__global__ __launch_bounds__(256) void k_split2(
    const float* __restrict__ x, const float* __restrict__ emb,
    unsigned short* __restrict__ xh, unsigned short* __restrict__ xm,
    unsigned short* __restrict__ xl, unsigned short* __restrict__ eh,
    unsigned short* __restrict__ em, unsigned short* __restrict__ el,
    float* __restrict__ enorm, unsigned long long* __restrict__ keys,
    int* __restrict__ counts) {
    int b = blockIdx.x, t = threadIdx.x;
    if (b < 4224) {
        const float* src;
        unsigned short *ph, *pm, *pl;
        int i;
        if (b < 4096) { src = x; ph = xh; pm = xm; pl = xl; i = b * 256 + t; }
        else { src = emb; ph = eh; pm = em; pl = el; i = (b - 4096) * 256 + t; }
        const float4* xp = (const float4*)src;
        float4 a = xp[i * 2], c = xp[i * 2 + 1];
        float v[8] = {a.x, a.y, a.z, a.w, c.x, c.y, c.z, c.w};
        short8 H, M, L;
#pragma unroll
        for (int u = 0; u < 8; ++u) {
            unsigned short h = f2bf(v[u]);
            float r1 = v[u] - bf2f(h);
            unsigned short m = f2bf(r1);
            float r2 = r1 - bf2f(m);
            unsigned short lo = f2bf(r2);
            H[u] = (short)h; M[u] = (short)m; L[u] = (short)lo;
        }
        *(short8*)&ph[(size_t)i * 8] = H;
        *(short8*)&pm[(size_t)i * 8] = M;
        *(short8*)&pl[(size_t)i * 8] = L;
        if (b < 128) keys[b * 256 + t] = 0xFFFFFFFFFFFFFFFFull;
        else if (b < 132) counts[(b - 128) * 256 + t] = 0;
    } else {
        // enorm — body verbatim from the passing k_enorm (same fp32 order)
        int blk = b - 4224;
        int w = t >> 6, lane = t & 63;
        int c = blk * 4 + w;
        const float4 v = *(const float4*)&emb[(size_t)c * DIM + lane * 4];
        float s = v.x * v.x + v.y * v.y + v.z * v.z + v.w * v.w;
#pragma unroll
        for (int m = 32; m; m >>= 1) s += __shfl_xor(s, m, 64);
        if (lane == 0) enorm[c] = s;
    }
}

// MFMA distance + fused argmin. 6-term split-bf16 emulated-fp32 GEMM.
// K-loop: 8 chunks of BK=32; per chunk stage all 6 unique planes (48 KB)
// ONCE, then compute all 6 terms reusing fragments in registers.
// Staged bytes/block 768->384 KB; ds_reads halved; 96 MFMA/wave per barrier.
__global__ __launch_bounds__(256) void k_distm(
    const unsigned short* __restrict__ xh, const unsigned short* __restrict__ xm,
    const unsigned short* __restrict__ xl, const unsigned short* __restrict__ eh,
    const unsigned short* __restrict__ em, const unsigned short* __restrict__ el,
    const float* __restrict__ enorm, unsigned long long* __restrict__ keys) {
    // plane p (0..5 = xh,xm,xl,eh,em,el): 8 subtiles x 512 bf16 = 8 KB each
    __shared__ unsigned short S[6][4096];  // 48 KB

    const int t = threadIdx.x;
    const int l = t & 63, w = t >> 6;
    const int wr = w >> 1, wc = w & 1;
    const int b = blockIdx.x;
    const int logical = (b & 7) * 256 + (b >> 3);  // bijective: 2048 % 8 == 0
    const int brow = (logical >> 3) * 128;
    const int bcol = (logical & 7) * 128;

    float en[4];
    int cidx[4];
#pragma unroll
    for (int j = 0; j < 4; ++j) {
        cidx[j] = bcol + wc * 64 + j * 16 + (l & 15);
        en[j] = enorm[cidx[j]];
    }

    f32x4 acc[4][4] = {};

    const int rlane = l & 15;          // row/col within 16-group
    const int klane = (l >> 4) * 8;    // k offset within 32-k subtile

    for (int s = 0; s < 8; ++s) {
        const int k0 = s * 32;
        __syncthreads();
        // stage 48 subtiles; wave w stages 12 (compile-time plane indices)
        if (w == 0) {
#pragma unroll
            for (int sg = 0; sg < 8; ++sg)
                gload_lds16(&xh[(size_t)(brow + sg * 16 + rlane) * 256 + k0 + klane],
                            &S[0][sg * 512]);
#pragma unroll
            for (int sg = 0; sg < 4; ++sg)
                gload_lds16(&xm[(size_t)(brow + sg * 16 + rlane) * 256 + k0 + klane],
                            &S[1][sg * 512]);
        } else if (w == 1) {
#pragma unroll
            for (int sg = 4; sg < 8; ++sg)
                gload_lds16(&xm[(size_t)(brow + sg * 16 + rlane) * 256 + k0 + klane],
                            &S[1][sg * 512]);
#pragma unroll
            for (int sg = 0; sg < 8; ++sg)
                gload_lds16(&xl[(size_t)(brow + sg * 16 + rlane) * 256 + k0 + klane],
                            &S[2][sg * 512]);
        } else if (w == 2) {
#pragma unroll
            for (int sg = 0; sg < 8; ++sg)
                gload_lds16(&eh[(size_t)(bcol + sg * 16 + rlane) * 256 + k0 + klane],
                            &S[3][sg * 512]);
#pragma unroll
            for (int sg = 0; sg < 4; ++sg)
                gload_lds16(&em[(size_t)(bcol + sg * 16 + rlane) * 256 + k0 + klane],
                            &S[4][sg * 512]);
        } else {
#pragma unroll
            for (int sg = 4; sg < 8; ++sg)
                gload_lds16(&em[(size_t)(bcol + sg * 16 + rlane) * 256 + k0 + klane],
                            &S[4][sg * 512]);
#pragma unroll
            for (int sg = 0; sg < 8; ++sg)
                gload_lds16(&el[(size_t)(bcol + sg * 16 + rlane) * 256 + k0 + klane],
                            &S[5][sg * 512]);
        }
        __syncthreads();  // waitcnt vmcnt(0) + barrier: all planes staged

        // fragments: a* from S[0..2] subtiles wr*4+i, b* from S[3..5] wc*4+j
        short8 ah[4], bh[4], am[4], bm[4], bl[4], al[4];
#pragma unroll
        for (int i = 0; i < 4; ++i)
            ah[i] = *(const short8*)&S[0][(wr * 4 + i) * 512 + l * 8];
#pragma unroll
        for (int j = 0; j < 4; ++j)
            bh[j] = *(const short8*)&S[3][(wc * 4 + j) * 512 + l * 8];
        // term hh
#pragma unroll
        for (int i = 0; i < 4; ++i)
#pragma unroll
            for (int j = 0; j < 4; ++j)
                acc[i][j] = __builtin_amdgcn_mfma_f32_16x16x32_bf16(
                    ah[i], bh[j], acc[i][j], 0, 0, 0);
#pragma unroll
        for (int j = 0; j < 4; ++j)
            bm[j] = *(const short8*)&S[4][(wc * 4 + j) * 512 + l * 8];
        // term hm
#pragma unroll
        for (int i = 0; i < 4; ++i)
#pragma unroll
            for (int j = 0; j < 4; ++j)
                acc[i][j] = __builtin_amdgcn_mfma_f32_16x16x32_bf16(
                    ah[i], bm[j], acc[i][j], 0, 0, 0);
#pragma unroll
        for (int i = 0; i < 4; ++i)
            am[i] = *(const short8*)&S[1][(wr * 4 + i) * 512 + l * 8];
        // term mh
#pragma unroll
        for (int i = 0; i < 4; ++i)
#pragma unroll
            for (int j = 0; j < 4; ++j)
                acc[i][j] = __builtin_amdgcn_mfma_f32_16x16x32_bf16(
                    am[i], bh[j], acc[i][j], 0, 0, 0);
        // term mm
#pragma unroll
        for (int i = 0; i < 4; ++i)
#pragma unroll
            for (int j = 0; j < 4; ++j)
                acc[i][j] = __builtin_amdgcn_mfma_f32_16x16x32_bf16(
                    am[i], bm[j], acc[i][j], 0, 0, 0);
#pragma unroll
        for (int j = 0; j < 4; ++j)
            bl[j] = *(const short8*)&S[5][(wc * 4 + j) * 512 + l * 8];
        // term hl
#pragma unroll
        for (int i = 0; i < 4; ++i)
#pragma unroll
            for (int j = 0; j < 4; ++j)
                acc[i][j] = __builtin_amdgcn_mfma_f32_16x16x32_bf16(
                    ah[i], bl[j], acc[i][j], 0, 0, 0);
#pragma unroll
        for (int i = 0; i < 4; ++i)
            al[i] = *(const short8*)&S[2][(wr * 4 + i) * 512 + l * 8];
        // term lh
#pragma unroll
        for (int i = 0; i < 4; ++i)
#pragma unroll
            for (int j = 0; j < 4; ++j)
                acc[i][j] = __builtin_amdgcn_mfma_f32_16x16x32_bf16(
                    al[i], bh[j], acc[i][j], 0, 0, 0);
    }

    // epilogue: dist = ||e||^2 - 2 x.e ; per-row argmin over wave's 64 codes
    // C layout: col = lane&15 (code), row = (lane>>4)*4 + reg (x-row)
#pragma unroll
    for (int i = 0; i < 4; ++i) {
#pragma unroll
        for (int r = 0; r < 4; ++r) {
            float best = 3.0e38f;
            int bi = 0x7FFFFFFF;
#pragma unroll
            for (int j = 0; j < 4; ++j) {
                float d = en[j] - 2.0f * acc[i][j][r];
                if (d < best || (d == best && cidx[j] < bi)) { best = d; bi = cidx[j]; }
            }
#pragma unroll
            for (int m = 1; m < 16; m <<= 1) {
                float d2 = __shfl_xor(best, m, 64);
                int b2 = __shfl_xor(bi, m, 64);
                if (d2 < best || (d2 == best && b2 < bi)) { best = d2; bi = b2; }
            }
            if ((l & 15) == 0) {
                int grow = brow + wr * 64 + i * 16 + (l >> 4) * 4 + r;
                unsigned int fb = __float_as_uint(best);
                unsigned int key32 = (fb & 0x80000000u) ? ~fb : (fb | 0x80000000u);
                atomicMin(&keys[grow],
                          ((unsigned long long)key32 << 32) | (unsigned)bi);
            }
        }
    }
}

// gather quantized rows, straight-through output, loss partials, counts
__global__ __launch_bounds__(256) void k_scatter(const float* __restrict__ x,
                                                 const float* __restrict__ e,
                                                 const unsigned long long* __restrict__ keys,
                                                 float* __restrict__ out_q,
                                                 float* __restrict__ out_tok,
                                                 int* __restrict__ counts,
                                                 float* __restrict__ loss_part) {
    __shared__ float lred[4];
    int w = threadIdx.x >> 6, lane = threadIdx.x & 63;
    int n = blockIdx.x * 4 + w;
    int k = (int)(unsigned int)(keys[n] & 0xFFFFFFFFull);

    size_t xo = (size_t)n * DIM + lane * 4;
    size_t eo = (size_t)k * DIM + lane * 4;
    const float4 xv = *(const float4*)&x[xo];
    const float4 ev = *(const float4*)&e[eo];

    float4 q;
    q.x = xv.x + (ev.x - xv.x);
    q.y = xv.y + (ev.y - xv.y);
    q.z = xv.z + (ev.z - xv.z);
    q.w = xv.w + (ev.w - xv.w);
    *(float4*)&out_q[xo] = q;

    float dx = xv.x - ev.x, dy = xv.y - ev.y, dz = xv.z - ev.z, dw = xv.w - ev.w;
    float ls = dx * dx + dy * dy + dz * dz + dw * dw;
#pragma unroll
    for (int m = 32; m; m >>= 1) ls += __shfl_xor(ls, m, 64);
    if (lane == 0) {
        lred[w] = ls;
        atomicAdd(&counts[k], 1);
        out_tok[n] = (float)k;
    }

    __syncthreads();
    if (threadIdx.x == 0)
        loss_part[blockIdx.x] = lred[0] + lred[1] + lred[2] + lred[3];
}

// fused: loss reduce + EMA cluster size + total, then prefix scan of counts
__global__ __launch_bounds__(1024) void k_mid(const float* __restrict__ cs,
                                              const int* __restrict__ counts,
                                              const float* __restrict__ loss_part,
                                              float* __restrict__ out_loss,
                                              float* __restrict__ out_ncs,
                                              float* __restrict__ ws_total,
                                              int* __restrict__ offsets,
                                              int* __restrict__ cursor) {
    __shared__ float red[1024];
    __shared__ int si[1024];
    int t = threadIdx.x;

    float ls = 0.0f;
    for (int i = t; i < 8192; i += 1024) ls += loss_part[i];
    red[t] = ls;
    __syncthreads();
    for (int s = 512; s; s >>= 1) {
        if (t < s) red[t] += red[t + s];
        __syncthreads();
    }
    if (t == 0) out_loss[0] = red[0] / 8388608.0f;
    __syncthreads();

    float ncs = cs[t] * DECAYF + (1.0f - DECAYF) * (float)counts[t];
    out_ncs[t] = ncs;
    red[t] = ncs;
    __syncthreads();
    for (int s = 512; s; s >>= 1) {
        if (t < s) red[t] += red[t + s];
        __syncthreads();
    }
    if (t == 0) ws_total[0] = red[0];
    __syncthreads();

    int c = counts[t];
    si[t] = c;
    __syncthreads();
    for (int off = 1; off < 1024; off <<= 1) {
        int v = (t >= off) ? si[t - off] : 0;
        __syncthreads();
        si[t] += v;
        __syncthreads();
    }
    int excl = si[t] - c;
    offsets[t] = excl;
    cursor[t] = excl;
}

// group row ids by code
__global__ __launch_bounds__(256) void k_bucket(const unsigned long long* __restrict__ keys,
                                                int* __restrict__ cursor,
                                                int* __restrict__ bucket) {
    int n = blockIdx.x * 256 + threadIdx.x;
    int k = (int)(unsigned int)(keys[n] & 0xFFFFFFFFull);
    int slot = atomicAdd(&cursor[k], 1);
    bucket[slot] = n;
}

// per-code: sum bucketed x rows, then EMA avg + normalized embedding
__global__ __launch_bounds__(256) void k_embfinal(
    const float* __restrict__ x, const int* __restrict__ bucket,
    const int* __restrict__ offsets, const int* __restrict__ counts,
    const float* __restrict__ avg, const float* __restrict__ out_ncs,
    const float* __restrict__ ws_total, float* __restrict__ out_emb,
    float* __restrict__ out_avg) {
    int k = blockIdx.x, d = threadIdx.x;
    int off = offsets[k], cnt = counts[k];

    float sum = 0.0f;
    int i = off;
    for (; i + 4 <= off + cnt; i += 4) {
        int r0 = bucket[i], r1 = bucket[i + 1], r2 = bucket[i + 2], r3 = bucket[i + 3];
        float v0 = x[(size_t)r0 * DIM + d];
        float v1 = x[(size_t)r1 * DIM + d];
        float v2 = x[(size_t)r2 * DIM + d];
        float v3 = x[(size_t)r3 * DIM + d];
        sum += v0; sum += v1; sum += v2; sum += v3;
    }
    for (; i < off + cnt; ++i) sum += x[(size_t)bucket[i] * DIM + d];

    float total = ws_total[0];
    float ncs = out_ncs[k];
    float normalized = (ncs + EPSF) / (total + (float)KCODES * EPSF) * total;

    float na = avg[(size_t)k * DIM + d] * DECAYF + (1.0f - DECAYF) * sum;
    out_avg[(size_t)k * DIM + d] = na;
    out_emb[(size_t)k * DIM + d] = na / normalized;
}

extern "C" void kernel_launch(void* const* d_in, const int* in_sizes, int n_in,
                              void* d_out, int out_size, void* d_ws, size_t ws_size,
                              hipStream_t stream) {
    const float* x   = (const float*)d_in[0];
    const float* emb = (const float*)d_in[1];
    const float* cs  = (const float*)d_in[2];
    const float* avg = (const float*)d_in[3];

    float* out      = (float*)d_out;
    float* out_q    = out;
    float* out_tok  = out + 8388608;
    float* out_loss = out + 8421376;
    float* out_emb  = out + 8421377;
    float* out_ncs  = out + 8683521;
    float* out_avg  = out + 8684545;

    char* ws = (char*)d_ws;
    unsigned short* xh = (unsigned short*)(ws + 0);
    unsigned short* xm = (unsigned short*)(ws + 16777216);
    unsigned short* xl = (unsigned short*)(ws + 33554432);
    unsigned short* eh = (unsigned short*)(ws + 50331648);
    unsigned short* em = (unsigned short*)(ws + 50855936);
    unsigned short* el = (unsigned short*)(ws + 51380224);
    unsigned long long* keys = (unsigned long long*)(ws + 51904512);
    int* counts      = (int*)(ws + 52166656);
    int* offsets     = (int*)(ws + 52170752);
    int* cursor      = (int*)(ws + 52174848);
    int* bucket      = (int*)(ws + 52178944);
    float* loss_part = (float*)(ws + 52310016);
    float* enorm     = (float*)(ws + 52342784);
    float* ws_total  = (float*)(ws + 52346880);

    k_split2<<<4480, 256, 0, stream>>>(x, emb, xh, xm, xl, eh, em, el,
                                       enorm, keys, counts);
    k_distm<<<2048, 256, 0, stream>>>(xh, xm, xl, eh, em, el, enorm, keys);
    k_scatter<<<NROWS / 4, 256, 0, stream>>>(x, emb, keys, out_q, out_tok,
                                             counts, loss_part);
    k_mid<<<1, 1024, 0, stream>>>(cs, counts, loss_part, out_loss, out_ncs,
                                  ws_total, offsets, cursor);
    k_bucket<<<NROWS / 256, 256, 0, stream>>>(keys, cursor, bucket);
    k_embfinal<<<KCODES, 256, 0, stream>>>(x, bucket, offsets, counts, avg,
                                           out_ncs, ws_total, out_emb, out_avg);
}

// Round 11
// 303.532 us; speedup vs baseline: 2.5764x; 1.0504x over previous
//
#include <hip/hip_runtime.h>

#define NROWS 32768
#define DIM 256
#define KCODES 1024
#define DECAYF 0.99f
#define EPSF 1e-5f

typedef float f32x4 __attribute__((ext_vector_type(4)));
typedef short short8 __attribute__((ext_vector_type(8)));

// ---------------- workspace layout (bytes), ~52.3 MB ----------------
// xh: 0          xm: 16777216   xl: 33554432          (each 16 MB)
// eh: 50331648   em: 50855936   el: 51380224          (each 512 KB)
// keys u64[32768]:   51904512   (256 KB)
// counts int[1024]:  52166656
// offsets int[1024]: 52170752
// cursor int[1024]:  52174848
// bucket int[32768]: 52178944   (128 KB)
// loss_part[8192]:   52310016   (32 KB)
// enorm[1024]:       52342784
// ws_total:          52346880

__device__ inline unsigned short f2bf(float f) {
    unsigned u = __float_as_uint(f);
    return (unsigned short)((u + 0x7FFFu + ((u >> 16) & 1u)) >> 16);
}
__device__ inline float bf2f(unsigned short h) {
    return __uint_as_float(((unsigned)h) << 16);
}

// async global->LDS, 16B per lane; LDS dest = wave-uniform base + lane*16
__device__ __forceinline__ void gload_lds16(const void* g, void* l) {
    __builtin_amdgcn_global_load_lds(
        (const __attribute__((address_space(1))) unsigned int*)g,
        (__attribute__((address_space(3))) unsigned int*)l, 16, 0, 0);
}

// fused: split x+emb into 3 bf16 planes, init keys/counts, enorm (verbatim)
__global__ __launch_bounds__(256) void k_split2(
    const float* __restrict__ x, const float* __restrict__ emb,
    unsigned short* __restrict__ xh, unsigned short* __restrict__ xm,
    unsigned short* __restrict__ xl, unsigned short* __restrict__ eh,
    unsigned short* __restrict__ em, unsigned short* __restrict__ el,
    float* __restrict__ enorm, unsigned long long* __restrict__ keys,
    int* __restrict__ counts) {
    int b = blockIdx.x, t = threadIdx.x;
    if (b < 4224) {
        const float* src;
        unsigned short *ph, *pm, *pl;
        int i;
        if (b < 4096) { src = x; ph = xh; pm = xm; pl = xl; i = b * 256 + t; }
        else { src = emb; ph = eh; pm = em; pl = el; i = (b - 4096) * 256 + t; }
        const float4* xp = (const float4*)src;
        float4 a = xp[i * 2], c = xp[i * 2 + 1];
        float v[8] = {a.x, a.y, a.z, a.w, c.x, c.y, c.z, c.w};
        short8 H, M, L;
#pragma unroll
        for (int u = 0; u < 8; ++u) {
            unsigned short h = f2bf(v[u]);
            float r1 = v[u] - bf2f(h);
            unsigned short m = f2bf(r1);
            float r2 = r1 - bf2f(m);
            unsigned short lo = f2bf(r2);
            H[u] = (short)h; M[u] = (short)m; L[u] = (short)lo;
        }
        *(short8*)&ph[(size_t)i * 8] = H;
        *(short8*)&pm[(size_t)i * 8] = M;
        *(short8*)&pl[(size_t)i * 8] = L;
        if (b < 128) keys[b * 256 + t] = 0xFFFFFFFFFFFFFFFFull;
        else if (b < 132) counts[(b - 128) * 256 + t] = 0;
    } else {
        int blk = b - 4224;
        int w = t >> 6, lane = t & 63;
        int c = blk * 4 + w;
        const float4 v = *(const float4*)&emb[(size_t)c * DIM + lane * 4];
        float s = v.x * v.x + v.y * v.y + v.z * v.z + v.w * v.w;
#pragma unroll
        for (int m = 32; m; m >>= 1) s += __shfl_xor(s, m, 64);
        if (lane == 0) enorm[c] = s;
    }
}

// MFMA distance + fused argmin. 6-term split-bf16 emulated-fp32 GEMM.
// Counted-vmcnt phased schedule (T3+T4): per chunk each wave issues its 12
// plane-loads in consumption order (S0,S3 | S4 | S1 | S5 | S2 pairs), then
// phases: vmcnt(8) hh | vmcnt(6) hm | vmcnt(4) mh+mm | vmcnt(2) hl |
// vmcnt(0) lh. Later loads stay in flight under earlier MFMA. Term order
// and operands identical to the passing round-10 kernel.
// NOTE: no other VMEM ops inside the loop (enorm moved to epilogue) so the
// vmcnt counts are exact.
__global__ __launch_bounds__(256, 3) void k_distm(
    const unsigned short* __restrict__ xh, const unsigned short* __restrict__ xm,
    const unsigned short* __restrict__ xl, const unsigned short* __restrict__ eh,
    const unsigned short* __restrict__ em, const unsigned short* __restrict__ el,
    const float* __restrict__ enorm, unsigned long long* __restrict__ keys) {
    // plane p (0..5 = xh,xm,xl,eh,em,el): 8 subtiles x 512 bf16 = 8 KB each
    __shared__ unsigned short S[6][4096];  // 48 KB

    const int t = threadIdx.x;
    const int l = t & 63, w = t >> 6;
    const int wr = w >> 1, wc = w & 1;
    const int b = blockIdx.x;
    const int logical = (b & 7) * 256 + (b >> 3);  // bijective: 2048 % 8 == 0
    const int brow = (logical >> 3) * 128;
    const int bcol = (logical & 7) * 128;

    f32x4 acc[4][4] = {};

    const int rlane = l & 15;          // row/col within 16-group
    const int klane = (l >> 4) * 8;    // k offset within 32-k subtile
    const int sg0 = 2 * w, sg1 = 2 * w + 1;   // this wave's subtile pair
    const size_t ra0 = (size_t)(brow + sg0 * 16 + rlane) * 256 + klane;
    const size_t ra1 = (size_t)(brow + sg1 * 16 + rlane) * 256 + klane;
    const size_t ca0 = (size_t)(bcol + sg0 * 16 + rlane) * 256 + klane;
    const size_t ca1 = (size_t)(bcol + sg1 * 16 + rlane) * 256 + klane;

    for (int s = 0; s < 8; ++s) {
        const int k0 = s * 32;
        __builtin_amdgcn_s_barrier();  // all waves done reading prev chunk
        // issue 12 loads in consumption order: S0,S3 | S4 | S1 | S5 | S2
        gload_lds16(&xh[ra0 + k0], &S[0][sg0 * 512]);
        gload_lds16(&xh[ra1 + k0], &S[0][sg1 * 512]);
        gload_lds16(&eh[ca0 + k0], &S[3][sg0 * 512]);
        gload_lds16(&eh[ca1 + k0], &S[3][sg1 * 512]);
        gload_lds16(&em[ca0 + k0], &S[4][sg0 * 512]);
        gload_lds16(&em[ca1 + k0], &S[4][sg1 * 512]);
        gload_lds16(&xm[ra0 + k0], &S[1][sg0 * 512]);
        gload_lds16(&xm[ra1 + k0], &S[1][sg1 * 512]);
        gload_lds16(&el[ca0 + k0], &S[5][sg0 * 512]);
        gload_lds16(&el[ca1 + k0], &S[5][sg1 * 512]);
        gload_lds16(&xl[ra0 + k0], &S[2][sg0 * 512]);
        gload_lds16(&xl[ra1 + k0], &S[2][sg1 * 512]);

        short8 ah[4], bh[4], am[4], bm[4], bl[4], al[4];

        asm volatile("s_waitcnt vmcnt(8)" ::: "memory");
        __builtin_amdgcn_s_barrier();   // S0,S3 visible
#pragma unroll
        for (int i = 0; i < 4; ++i)
            ah[i] = *(const short8*)&S[0][(wr * 4 + i) * 512 + l * 8];
#pragma unroll
        for (int j = 0; j < 4; ++j)
            bh[j] = *(const short8*)&S[3][(wc * 4 + j) * 512 + l * 8];
        __builtin_amdgcn_s_setprio(1);
#pragma unroll
        for (int i = 0; i < 4; ++i)
#pragma unroll
            for (int j = 0; j < 4; ++j)
                acc[i][j] = __builtin_amdgcn_mfma_f32_16x16x32_bf16(
                    ah[i], bh[j], acc[i][j], 0, 0, 0);
        __builtin_amdgcn_s_setprio(0);

        asm volatile("s_waitcnt vmcnt(6)" ::: "memory");
        __builtin_amdgcn_s_barrier();   // S4 visible
#pragma unroll
        for (int j = 0; j < 4; ++j)
            bm[j] = *(const short8*)&S[4][(wc * 4 + j) * 512 + l * 8];
        __builtin_amdgcn_s_setprio(1);
#pragma unroll
        for (int i = 0; i < 4; ++i)
#pragma unroll
            for (int j = 0; j < 4; ++j)
                acc[i][j] = __builtin_amdgcn_mfma_f32_16x16x32_bf16(
                    ah[i], bm[j], acc[i][j], 0, 0, 0);
        __builtin_amdgcn_s_setprio(0);

        asm volatile("s_waitcnt vmcnt(4)" ::: "memory");
        __builtin_amdgcn_s_barrier();   // S1 visible
#pragma unroll
        for (int i = 0; i < 4; ++i)
            am[i] = *(const short8*)&S[1][(wr * 4 + i) * 512 + l * 8];
        __builtin_amdgcn_s_setprio(1);
#pragma unroll
        for (int i = 0; i < 4; ++i)
#pragma unroll
            for (int j = 0; j < 4; ++j)
                acc[i][j] = __builtin_amdgcn_mfma_f32_16x16x32_bf16(
                    am[i], bh[j], acc[i][j], 0, 0, 0);
#pragma unroll
        for (int i = 0; i < 4; ++i)
#pragma unroll
            for (int j = 0; j < 4; ++j)
                acc[i][j] = __builtin_amdgcn_mfma_f32_16x16x32_bf16(
                    am[i], bm[j], acc[i][j], 0, 0, 0);
        __builtin_amdgcn_s_setprio(0);

        asm volatile("s_waitcnt vmcnt(2)" ::: "memory");
        __builtin_amdgcn_s_barrier();   // S5 visible
#pragma unroll
        for (int j = 0; j < 4; ++j)
            bl[j] = *(const short8*)&S[5][(wc * 4 + j) * 512 + l * 8];
        __builtin_amdgcn_s_setprio(1);
#pragma unroll
        for (int i = 0; i < 4; ++i)
#pragma unroll
            for (int j = 0; j < 4; ++j)
                acc[i][j] = __builtin_amdgcn_mfma_f32_16x16x32_bf16(
                    ah[i], bl[j], acc[i][j], 0, 0, 0);
        __builtin_amdgcn_s_setprio(0);

        asm volatile("s_waitcnt vmcnt(0)" ::: "memory");
        __builtin_amdgcn_s_barrier();   // S2 visible
#pragma unroll
        for (int i = 0; i < 4; ++i)
            al[i] = *(const short8*)&S[2][(wr * 4 + i) * 512 + l * 8];
        __builtin_amdgcn_s_setprio(1);
#pragma unroll
        for (int i = 0; i < 4; ++i)
#pragma unroll
            for (int j = 0; j < 4; ++j)
                acc[i][j] = __builtin_amdgcn_mfma_f32_16x16x32_bf16(
                    al[i], bh[j], acc[i][j], 0, 0, 0);
        __builtin_amdgcn_s_setprio(0);

        // ensure this wave's S2 reads are serviced before signaling the
        // loop-top barrier (next chunk overwrites S[0..5])
        asm volatile("s_waitcnt lgkmcnt(0)" ::: "memory");
    }

    // epilogue: dist = ||e||^2 - 2 x.e ; per-row argmin over wave's 64 codes
    // C layout: col = lane&15 (code), row = (lane>>4)*4 + reg (x-row)
    float en[4];
    int cidx[4];
#pragma unroll
    for (int j = 0; j < 4; ++j) {
        cidx[j] = bcol + wc * 64 + j * 16 + (l & 15);
        en[j] = enorm[cidx[j]];
    }
#pragma unroll
    for (int i = 0; i < 4; ++i) {
#pragma unroll
        for (int r = 0; r < 4; ++r) {
            float best = 3.0e38f;
            int bi = 0x7FFFFFFF;
#pragma unroll
            for (int j = 0; j < 4; ++j) {
                float d = en[j] - 2.0f * acc[i][j][r];
                if (d < best || (d == best && cidx[j] < bi)) { best = d; bi = cidx[j]; }
            }
#pragma unroll
            for (int m = 1; m < 16; m <<= 1) {
                float d2 = __shfl_xor(best, m, 64);
                int b2 = __shfl_xor(bi, m, 64);
                if (d2 < best || (d2 == best && b2 < bi)) { best = d2; bi = b2; }
            }
            if ((l & 15) == 0) {
                int grow = brow + wr * 64 + i * 16 + (l >> 4) * 4 + r;
                unsigned int fb = __float_as_uint(best);
                unsigned int key32 = (fb & 0x80000000u) ? ~fb : (fb | 0x80000000u);
                atomicMin(&keys[grow],
                          ((unsigned long long)key32 << 32) | (unsigned)bi);
            }
        }
    }
}

// gather quantized rows, straight-through output, loss partials, counts
__global__ __launch_bounds__(256) void k_scatter(const float* __restrict__ x,
                                                 const float* __restrict__ e,
                                                 const unsigned long long* __restrict__ keys,
                                                 float* __restrict__ out_q,
                                                 float* __restrict__ out_tok,
                                                 int* __restrict__ counts,
                                                 float* __restrict__ loss_part) {
    __shared__ float lred[4];
    int w = threadIdx.x >> 6, lane = threadIdx.x & 63;
    int n = blockIdx.x * 4 + w;
    int k = (int)(unsigned int)(keys[n] & 0xFFFFFFFFull);

    size_t xo = (size_t)n * DIM + lane * 4;
    size_t eo = (size_t)k * DIM + lane * 4;
    const float4 xv = *(const float4*)&x[xo];
    const float4 ev = *(const float4*)&e[eo];

    float4 q;
    q.x = xv.x + (ev.x - xv.x);
    q.y = xv.y + (ev.y - xv.y);
    q.z = xv.z + (ev.z - xv.z);
    q.w = xv.w + (ev.w - xv.w);
    *(float4*)&out_q[xo] = q;

    float dx = xv.x - ev.x, dy = xv.y - ev.y, dz = xv.z - ev.z, dw = xv.w - ev.w;
    float ls = dx * dx + dy * dy + dz * dz + dw * dw;
#pragma unroll
    for (int m = 32; m; m >>= 1) ls += __shfl_xor(ls, m, 64);
    if (lane == 0) {
        lred[w] = ls;
        atomicAdd(&counts[k], 1);
        out_tok[n] = (float)k;
    }

    __syncthreads();
    if (threadIdx.x == 0)
        loss_part[blockIdx.x] = lred[0] + lred[1] + lred[2] + lred[3];
}

// fused: loss reduce + EMA cluster size + total, then prefix scan of counts
__global__ __launch_bounds__(1024) void k_mid(const float* __restrict__ cs,
                                              const int* __restrict__ counts,
                                              const float* __restrict__ loss_part,
                                              float* __restrict__ out_loss,
                                              float* __restrict__ out_ncs,
                                              float* __restrict__ ws_total,
                                              int* __restrict__ offsets,
                                              int* __restrict__ cursor) {
    __shared__ float red[1024];
    __shared__ int si[1024];
    int t = threadIdx.x;

    float ls = 0.0f;
    for (int i = t; i < 8192; i += 1024) ls += loss_part[i];
    red[t] = ls;
    __syncthreads();
    for (int s = 512; s; s >>= 1) {
        if (t < s) red[t] += red[t + s];
        __syncthreads();
    }
    if (t == 0) out_loss[0] = red[0] / 8388608.0f;
    __syncthreads();

    float ncs = cs[t] * DECAYF + (1.0f - DECAYF) * (float)counts[t];
    out_ncs[t] = ncs;
    red[t] = ncs;
    __syncthreads();
    for (int s = 512; s; s >>= 1) {
        if (t < s) red[t] += red[t + s];
        __syncthreads();
    }
    if (t == 0) ws_total[0] = red[0];
    __syncthreads();

    int c = counts[t];
    si[t] = c;
    __syncthreads();
    for (int off = 1; off < 1024; off <<= 1) {
        int v = (t >= off) ? si[t - off] : 0;
        __syncthreads();
        si[t] += v;
        __syncthreads();
    }
    int excl = si[t] - c;
    offsets[t] = excl;
    cursor[t] = excl;
}

// group row ids by code
__global__ __launch_bounds__(256) void k_bucket(const unsigned long long* __restrict__ keys,
                                                int* __restrict__ cursor,
                                                int* __restrict__ bucket) {
    int n = blockIdx.x * 256 + threadIdx.x;
    int k = (int)(unsigned int)(keys[n] & 0xFFFFFFFFull);
    int slot = atomicAdd(&cursor[k], 1);
    bucket[slot] = n;
}

// per-code: sum bucketed x rows, then EMA avg + normalized embedding
__global__ __launch_bounds__(256) void k_embfinal(
    const float* __restrict__ x, const int* __restrict__ bucket,
    const int* __restrict__ offsets, const int* __restrict__ counts,
    const float* __restrict__ avg, const float* __restrict__ out_ncs,
    const float* __restrict__ ws_total, float* __restrict__ out_emb,
    float* __restrict__ out_avg) {
    int k = blockIdx.x, d = threadIdx.x;
    int off = offsets[k], cnt = counts[k];

    float sum = 0.0f;
    int i = off;
    for (; i + 4 <= off + cnt; i += 4) {
        int r0 = bucket[i], r1 = bucket[i + 1], r2 = bucket[i + 2], r3 = bucket[i + 3];
        float v0 = x[(size_t)r0 * DIM + d];
        float v1 = x[(size_t)r1 * DIM + d];
        float v2 = x[(size_t)r2 * DIM + d];
        float v3 = x[(size_t)r3 * DIM + d];
        sum += v0; sum += v1; sum += v2; sum += v3;
    }
    for (; i < off + cnt; ++i) sum += x[(size_t)bucket[i] * DIM + d];

    float total = ws_total[0];
    float ncs = out_ncs[k];
    float normalized = (ncs + EPSF) / (total + (float)KCODES * EPSF) * total;

    float na = avg[(size_t)k * DIM + d] * DECAYF + (1.0f - DECAYF) * sum;
    out_avg[(size_t)k * DIM + d] = na;
    out_emb[(size_t)k * DIM + d] = na / normalized;
}

extern "C" void kernel_launch(void* const* d_in, const int* in_sizes, int n_in,
                              void* d_out, int out_size, void* d_ws, size_t ws_size,
                              hipStream_t stream) {
    const float* x   = (const float*)d_in[0];
    const float* emb = (const float*)d_in[1];
    const float* cs  = (const float*)d_in[2];
    const float* avg = (const float*)d_in[3];

    float* out      = (float*)d_out;
    float* out_q    = out;
    float* out_tok  = out + 8388608;
    float* out_loss = out + 8421376;
    float* out_emb  = out + 8421377;
    float* out_ncs  = out + 8683521;
    float* out_avg  = out + 8684545;

    char* ws = (char*)d_ws;
    unsigned short* xh = (unsigned short*)(ws + 0);
    unsigned short* xm = (unsigned short*)(ws + 16777216);
    unsigned short* xl = (unsigned short*)(ws + 33554432);
    unsigned short* eh = (unsigned short*)(ws + 50331648);
    unsigned short* em = (unsigned short*)(ws + 50855936);
    unsigned short* el = (unsigned short*)(ws + 51380224);
    unsigned long long* keys = (unsigned long long*)(ws + 51904512);
    int* counts      = (int*)(ws + 52166656);
    int* offsets     = (int*)(ws + 52170752);
    int* cursor      = (int*)(ws + 52174848);
    int* bucket      = (int*)(ws + 52178944);
    float* loss_part = (float*)(ws + 52310016);
    float* enorm     = (float*)(ws + 52342784);
    float* ws_total  = (float*)(ws + 52346880);

    k_split2<<<4480, 256, 0, stream>>>(x, emb, xh, xm, xl, eh, em, el,
                                       enorm, keys, counts);
    k_distm<<<2048, 256, 0, stream>>>(xh, xm, xl, eh, em, el, enorm, keys);
    k_scatter<<<NROWS / 4, 256, 0, stream>>>(x, emb, keys, out_q, out_tok,
                                             counts, loss_part);
    k_mid<<<1, 1024, 0, stream>>>(cs, counts, loss_part, out_loss, out_ncs,
                                  ws_total, offsets, cursor);
    k_bucket<<<NROWS / 256, 256, 0, stream>>>(keys, cursor, bucket);
    k_embfinal<<<KCODES, 256, 0, stream>>>(x, bucket, offsets, counts, avg,
                                           out_ncs, ws_total, out_emb, out_avg);
}

// Round 12
// 202.400 us; speedup vs baseline: 3.8637x; 1.4997x over previous
//
#include <hip/hip_runtime.h>

#define NROWS 32768
#define DIM 256
#define KCODES 1024
#define DECAYF 0.99f
#define EPSF 1e-5f

typedef float f32x4 __attribute__((ext_vector_type(4)));
typedef short short8 __attribute__((ext_vector_type(8)));

// ---------------- workspace layout (bytes), ~52.3 MB ----------------
// xh: 0          xm: 16777216   xl: 33554432          (each 16 MB)
//   (partial[4][1024][256] f32, 4 MB, ALIASES xh after k_distm is done)
// eh: 50331648   em: 50855936   el: 51380224          (each 512 KB)
// keys u64[32768]:   51904512   (256 KB)
// counts int[1024]:  52166656
// offsets int[1024]: 52170752
// cursor int[1024]:  52174848
// bucket int[32768]: 52178944   (128 KB)
// loss_part[8192]:   52310016   (32 KB)
// enorm[1024]:       52342784
// ws_total:          52346880

__device__ inline unsigned short f2bf(float f) {
    unsigned u = __float_as_uint(f);
    return (unsigned short)((u + 0x7FFFu + ((u >> 16) & 1u)) >> 16);
}
__device__ inline float bf2f(unsigned short h) {
    return __uint_as_float(((unsigned)h) << 16);
}

// async global->LDS, 16B per lane; LDS dest = wave-uniform base + lane*16
__device__ __forceinline__ void gload_lds16(const void* g, void* l) {
    __builtin_amdgcn_global_load_lds(
        (const __attribute__((address_space(1))) unsigned int*)g,
        (__attribute__((address_space(3))) unsigned int*)l, 16, 0, 0);
}

// fused: split x+emb into 3 bf16 planes, init keys/counts, enorm (verbatim)
__global__ __launch_bounds__(256) void k_split2(
    const float* __restrict__ x, const float* __restrict__ emb,
    unsigned short* __restrict__ xh, unsigned short* __restrict__ xm,
    unsigned short* __restrict__ xl, unsigned short* __restrict__ eh,
    unsigned short* __restrict__ em, unsigned short* __restrict__ el,
    float* __restrict__ enorm, unsigned long long* __restrict__ keys,
    int* __restrict__ counts) {
    int b = blockIdx.x, t = threadIdx.x;
    if (b < 4224) {
        const float* src;
        unsigned short *ph, *pm, *pl;
        int i;
        if (b < 4096) { src = x; ph = xh; pm = xm; pl = xl; i = b * 256 + t; }
        else { src = emb; ph = eh; pm = em; pl = el; i = (b - 4096) * 256 + t; }
        const float4* xp = (const float4*)src;
        float4 a = xp[i * 2], c = xp[i * 2 + 1];
        float v[8] = {a.x, a.y, a.z, a.w, c.x, c.y, c.z, c.w};
        short8 H, M, L;
#pragma unroll
        for (int u = 0; u < 8; ++u) {
            unsigned short h = f2bf(v[u]);
            float r1 = v[u] - bf2f(h);
            unsigned short m = f2bf(r1);
            float r2 = r1 - bf2f(m);
            unsigned short lo = f2bf(r2);
            H[u] = (short)h; M[u] = (short)m; L[u] = (short)lo;
        }
        *(short8*)&ph[(size_t)i * 8] = H;
        *(short8*)&pm[(size_t)i * 8] = M;
        *(short8*)&pl[(size_t)i * 8] = L;
        if (b < 128) keys[b * 256 + t] = 0xFFFFFFFFFFFFFFFFull;
        else if (b < 132) counts[(b - 128) * 256 + t] = 0;
    } else {
        int blk = b - 4224;
        int w = t >> 6, lane = t & 63;
        int c = blk * 4 + w;
        const float4 v = *(const float4*)&emb[(size_t)c * DIM + lane * 4];
        float s = v.x * v.x + v.y * v.y + v.z * v.z + v.w * v.w;
#pragma unroll
        for (int m = 32; m; m >>= 1) s += __shfl_xor(s, m, 64);
        if (lane == 0) enorm[c] = s;
    }
}

// MFMA distance + fused argmin. 6-term split-bf16 emulated-fp32 GEMM.
// Counted-vmcnt phased schedule (unchanged from passing round-11 kernel).
__global__ __launch_bounds__(256, 3) void k_distm(
    const unsigned short* __restrict__ xh, const unsigned short* __restrict__ xm,
    const unsigned short* __restrict__ xl, const unsigned short* __restrict__ eh,
    const unsigned short* __restrict__ em, const unsigned short* __restrict__ el,
    const float* __restrict__ enorm, unsigned long long* __restrict__ keys) {
    __shared__ unsigned short S[6][4096];  // 48 KB

    const int t = threadIdx.x;
    const int l = t & 63, w = t >> 6;
    const int wr = w >> 1, wc = w & 1;
    const int b = blockIdx.x;
    const int logical = (b & 7) * 256 + (b >> 3);  // bijective: 2048 % 8 == 0
    const int brow = (logical >> 3) * 128;
    const int bcol = (logical & 7) * 128;

    f32x4 acc[4][4] = {};

    const int rlane = l & 15;
    const int klane = (l >> 4) * 8;
    const int sg0 = 2 * w, sg1 = 2 * w + 1;
    const size_t ra0 = (size_t)(brow + sg0 * 16 + rlane) * 256 + klane;
    const size_t ra1 = (size_t)(brow + sg1 * 16 + rlane) * 256 + klane;
    const size_t ca0 = (size_t)(bcol + sg0 * 16 + rlane) * 256 + klane;
    const size_t ca1 = (size_t)(bcol + sg1 * 16 + rlane) * 256 + klane;

    for (int s = 0; s < 8; ++s) {
        const int k0 = s * 32;
        __builtin_amdgcn_s_barrier();
        gload_lds16(&xh[ra0 + k0], &S[0][sg0 * 512]);
        gload_lds16(&xh[ra1 + k0], &S[0][sg1 * 512]);
        gload_lds16(&eh[ca0 + k0], &S[3][sg0 * 512]);
        gload_lds16(&eh[ca1 + k0], &S[3][sg1 * 512]);
        gload_lds16(&em[ca0 + k0], &S[4][sg0 * 512]);
        gload_lds16(&em[ca1 + k0], &S[4][sg1 * 512]);
        gload_lds16(&xm[ra0 + k0], &S[1][sg0 * 512]);
        gload_lds16(&xm[ra1 + k0], &S[1][sg1 * 512]);
        gload_lds16(&el[ca0 + k0], &S[5][sg0 * 512]);
        gload_lds16(&el[ca1 + k0], &S[5][sg1 * 512]);
        gload_lds16(&xl[ra0 + k0], &S[2][sg0 * 512]);
        gload_lds16(&xl[ra1 + k0], &S[2][sg1 * 512]);

        short8 ah[4], bh[4], am[4], bm[4], bl[4], al[4];

        asm volatile("s_waitcnt vmcnt(8)" ::: "memory");
        __builtin_amdgcn_s_barrier();
#pragma unroll
        for (int i = 0; i < 4; ++i)
            ah[i] = *(const short8*)&S[0][(wr * 4 + i) * 512 + l * 8];
#pragma unroll
        for (int j = 0; j < 4; ++j)
            bh[j] = *(const short8*)&S[3][(wc * 4 + j) * 512 + l * 8];
        __builtin_amdgcn_s_setprio(1);
#pragma unroll
        for (int i = 0; i < 4; ++i)
#pragma unroll
            for (int j = 0; j < 4; ++j)
                acc[i][j] = __builtin_amdgcn_mfma_f32_16x16x32_bf16(
                    ah[i], bh[j], acc[i][j], 0, 0, 0);
        __builtin_amdgcn_s_setprio(0);

        asm volatile("s_waitcnt vmcnt(6)" ::: "memory");
        __builtin_amdgcn_s_barrier();
#pragma unroll
        for (int j = 0; j < 4; ++j)
            bm[j] = *(const short8*)&S[4][(wc * 4 + j) * 512 + l * 8];
        __builtin_amdgcn_s_setprio(1);
#pragma unroll
        for (int i = 0; i < 4; ++i)
#pragma unroll
            for (int j = 0; j < 4; ++j)
                acc[i][j] = __builtin_amdgcn_mfma_f32_16x16x32_bf16(
                    ah[i], bm[j], acc[i][j], 0, 0, 0);
        __builtin_amdgcn_s_setprio(0);

        asm volatile("s_waitcnt vmcnt(4)" ::: "memory");
        __builtin_amdgcn_s_barrier();
#pragma unroll
        for (int i = 0; i < 4; ++i)
            am[i] = *(const short8*)&S[1][(wr * 4 + i) * 512 + l * 8];
        __builtin_amdgcn_s_setprio(1);
#pragma unroll
        for (int i = 0; i < 4; ++i)
#pragma unroll
            for (int j = 0; j < 4; ++j)
                acc[i][j] = __builtin_amdgcn_mfma_f32_16x16x32_bf16(
                    am[i], bh[j], acc[i][j], 0, 0, 0);
#pragma unroll
        for (int i = 0; i < 4; ++i)
#pragma unroll
            for (int j = 0; j < 4; ++j)
                acc[i][j] = __builtin_amdgcn_mfma_f32_16x16x32_bf16(
                    am[i], bm[j], acc[i][j], 0, 0, 0);
        __builtin_amdgcn_s_setprio(0);

        asm volatile("s_waitcnt vmcnt(2)" ::: "memory");
        __builtin_amdgcn_s_barrier();
#pragma unroll
        for (int j = 0; j < 4; ++j)
            bl[j] = *(const short8*)&S[5][(wc * 4 + j) * 512 + l * 8];
        __builtin_amdgcn_s_setprio(1);
#pragma unroll
        for (int i = 0; i < 4; ++i)
#pragma unroll
            for (int j = 0; j < 4; ++j)
                acc[i][j] = __builtin_amdgcn_mfma_f32_16x16x32_bf16(
                    ah[i], bl[j], acc[i][j], 0, 0, 0);
        __builtin_amdgcn_s_setprio(0);

        asm volatile("s_waitcnt vmcnt(0)" ::: "memory");
        __builtin_amdgcn_s_barrier();
#pragma unroll
        for (int i = 0; i < 4; ++i)
            al[i] = *(const short8*)&S[2][(wr * 4 + i) * 512 + l * 8];
        __builtin_amdgcn_s_setprio(1);
#pragma unroll
        for (int i = 0; i < 4; ++i)
#pragma unroll
            for (int j = 0; j < 4; ++j)
                acc[i][j] = __builtin_amdgcn_mfma_f32_16x16x32_bf16(
                    al[i], bh[j], acc[i][j], 0, 0, 0);
        __builtin_amdgcn_s_setprio(0);

        asm volatile("s_waitcnt lgkmcnt(0)" ::: "memory");
    }

    float en[4];
    int cidx[4];
#pragma unroll
    for (int j = 0; j < 4; ++j) {
        cidx[j] = bcol + wc * 64 + j * 16 + (l & 15);
        en[j] = enorm[cidx[j]];
    }
#pragma unroll
    for (int i = 0; i < 4; ++i) {
#pragma unroll
        for (int r = 0; r < 4; ++r) {
            float best = 3.0e38f;
            int bi = 0x7FFFFFFF;
#pragma unroll
            for (int j = 0; j < 4; ++j) {
                float d = en[j] - 2.0f * acc[i][j][r];
                if (d < best || (d == best && cidx[j] < bi)) { best = d; bi = cidx[j]; }
            }
#pragma unroll
            for (int m = 1; m < 16; m <<= 1) {
                float d2 = __shfl_xor(best, m, 64);
                int b2 = __shfl_xor(bi, m, 64);
                if (d2 < best || (d2 == best && b2 < bi)) { best = d2; bi = b2; }
            }
            if ((l & 15) == 0) {
                int grow = brow + wr * 64 + i * 16 + (l >> 4) * 4 + r;
                unsigned int fb = __float_as_uint(best);
                unsigned int key32 = (fb & 0x80000000u) ? ~fb : (fb | 0x80000000u);
                atomicMin(&keys[grow],
                          ((unsigned long long)key32 << 32) | (unsigned)bi);
            }
        }
    }
}

// gather quantized rows, straight-through output, loss partials, counts
__global__ __launch_bounds__(256) void k_scatter(const float* __restrict__ x,
                                                 const float* __restrict__ e,
                                                 const unsigned long long* __restrict__ keys,
                                                 float* __restrict__ out_q,
                                                 float* __restrict__ out_tok,
                                                 int* __restrict__ counts,
                                                 float* __restrict__ loss_part) {
    __shared__ float lred[4];
    int w = threadIdx.x >> 6, lane = threadIdx.x & 63;
    int n = blockIdx.x * 4 + w;
    int k = (int)(unsigned int)(keys[n] & 0xFFFFFFFFull);

    size_t xo = (size_t)n * DIM + lane * 4;
    size_t eo = (size_t)k * DIM + lane * 4;
    const float4 xv = *(const float4*)&x[xo];
    const float4 ev = *(const float4*)&e[eo];

    float4 q;
    q.x = xv.x + (ev.x - xv.x);
    q.y = xv.y + (ev.y - xv.y);
    q.z = xv.z + (ev.z - xv.z);
    q.w = xv.w + (ev.w - xv.w);
    *(float4*)&out_q[xo] = q;

    float dx = xv.x - ev.x, dy = xv.y - ev.y, dz = xv.z - ev.z, dw = xv.w - ev.w;
    float ls = dx * dx + dy * dy + dz * dz + dw * dw;
#pragma unroll
    for (int m = 32; m; m >>= 1) ls += __shfl_xor(ls, m, 64);
    if (lane == 0) {
        lred[w] = ls;
        atomicAdd(&counts[k], 1);
        out_tok[n] = (float)k;
    }

    __syncthreads();
    if (threadIdx.x == 0)
        loss_part[blockIdx.x] = lred[0] + lred[1] + lred[2] + lred[3];
}

// fused: loss reduce + EMA cluster size + total, then prefix scan of counts
__global__ __launch_bounds__(1024) void k_mid(const float* __restrict__ cs,
                                              const int* __restrict__ counts,
                                              const float* __restrict__ loss_part,
                                              float* __restrict__ out_loss,
                                              float* __restrict__ out_ncs,
                                              float* __restrict__ ws_total,
                                              int* __restrict__ offsets,
                                              int* __restrict__ cursor) {
    __shared__ float red[1024];
    __shared__ int si[1024];
    int t = threadIdx.x;

    float ls = 0.0f;
    for (int i = t; i < 8192; i += 1024) ls += loss_part[i];
    red[t] = ls;
    __syncthreads();
    for (int s = 512; s; s >>= 1) {
        if (t < s) red[t] += red[t + s];
        __syncthreads();
    }
    if (t == 0) out_loss[0] = red[0] / 8388608.0f;
    __syncthreads();

    float ncs = cs[t] * DECAYF + (1.0f - DECAYF) * (float)counts[t];
    out_ncs[t] = ncs;
    red[t] = ncs;
    __syncthreads();
    for (int s = 512; s; s >>= 1) {
        if (t < s) red[t] += red[t + s];
        __syncthreads();
    }
    if (t == 0) ws_total[0] = red[0];
    __syncthreads();

    int c = counts[t];
    si[t] = c;
    __syncthreads();
    for (int off = 1; off < 1024; off <<= 1) {
        int v = (t >= off) ? si[t - off] : 0;
        __syncthreads();
        si[t] += v;
        __syncthreads();
    }
    int excl = si[t] - c;
    offsets[t] = excl;
    cursor[t] = excl;
}

// group row ids by code
__global__ __launch_bounds__(256) void k_bucket(const unsigned long long* __restrict__ keys,
                                                int* __restrict__ cursor,
                                                int* __restrict__ bucket) {
    int n = blockIdx.x * 256 + threadIdx.x;
    int k = (int)(unsigned int)(keys[n] & 0xFFFFFFFFull);
    int slot = atomicAdd(&cursor[k], 1);
    bucket[slot] = n;
}

// per-(code, seg): partial row-sum with float4 loads, 4 waves x 4-deep ILP.
// partial[seg][code][dim] (aliases the dead xh region)
__global__ __launch_bounds__(256) void k_embpart(
    const float* __restrict__ x, const int* __restrict__ bucket,
    const int* __restrict__ offsets, const int* __restrict__ counts,
    float* __restrict__ partial) {
    __shared__ float lds[4][256];
    int k = blockIdx.x >> 2, s = blockIdx.x & 3;
    int w = threadIdx.x >> 6, lane = threadIdx.x & 63;
    int off = offsets[k], cnt = counts[k];
    int qcnt = (cnt + 3) >> 2;
    int start = off + s * qcnt;
    int lim = s * qcnt + qcnt;
    if (lim > cnt) lim = cnt;
    int end = off + lim;

    f32x4 acc = {0.0f, 0.0f, 0.0f, 0.0f};
    int i = start + w;
    for (; i + 12 < end; i += 16) {
        int r0 = bucket[i], r1 = bucket[i + 4], r2 = bucket[i + 8], r3 = bucket[i + 12];
        f32x4 v0 = *(const f32x4*)&x[(size_t)r0 * DIM + lane * 4];
        f32x4 v1 = *(const f32x4*)&x[(size_t)r1 * DIM + lane * 4];
        f32x4 v2 = *(const f32x4*)&x[(size_t)r2 * DIM + lane * 4];
        f32x4 v3 = *(const f32x4*)&x[(size_t)r3 * DIM + lane * 4];
        acc += v0; acc += v1; acc += v2; acc += v3;
    }
    for (; i < end; i += 4)
        acc += *(const f32x4*)&x[(size_t)bucket[i] * DIM + lane * 4];

    *(f32x4*)&lds[w][lane * 4] = acc;
    __syncthreads();
    int d = threadIdx.x;
    float sum = lds[0][d] + lds[1][d] + lds[2][d] + lds[3][d];
    partial[((size_t)s * KCODES + k) * DIM + d] = sum;
}

// combine 4 partials (fixed order) + EMA avg + normalized embedding
__global__ __launch_bounds__(256) void k_embfin2(
    const float* __restrict__ partial, const float* __restrict__ avg,
    const float* __restrict__ out_ncs, const float* __restrict__ ws_total,
    float* __restrict__ out_emb, float* __restrict__ out_avg) {
    int k = blockIdx.x, d = threadIdx.x;
    size_t o = (size_t)k * DIM + d;
    float sum = partial[(0 * KCODES + k) * DIM + d]
              + partial[(1 * KCODES + k) * DIM + d]
              + partial[(2 * KCODES + k) * DIM + d]
              + partial[(3 * KCODES + k) * DIM + d];

    float total = ws_total[0];
    float ncs = out_ncs[k];
    float normalized = (ncs + EPSF) / (total + (float)KCODES * EPSF) * total;

    float na = avg[o] * DECAYF + (1.0f - DECAYF) * sum;
    out_avg[o] = na;
    out_emb[o] = na / normalized;
}

extern "C" void kernel_launch(void* const* d_in, const int* in_sizes, int n_in,
                              void* d_out, int out_size, void* d_ws, size_t ws_size,
                              hipStream_t stream) {
    const float* x   = (const float*)d_in[0];
    const float* emb = (const float*)d_in[1];
    const float* cs  = (const float*)d_in[2];
    const float* avg = (const float*)d_in[3];

    float* out      = (float*)d_out;
    float* out_q    = out;
    float* out_tok  = out + 8388608;
    float* out_loss = out + 8421376;
    float* out_emb  = out + 8421377;
    float* out_ncs  = out + 8683521;
    float* out_avg  = out + 8684545;

    char* ws = (char*)d_ws;
    unsigned short* xh = (unsigned short*)(ws + 0);
    unsigned short* xm = (unsigned short*)(ws + 16777216);
    unsigned short* xl = (unsigned short*)(ws + 33554432);
    float* partial   = (float*)(ws + 0);   // aliases xh (dead after k_distm)
    unsigned short* eh = (unsigned short*)(ws + 50331648);
    unsigned short* em = (unsigned short*)(ws + 50855936);
    unsigned short* el = (unsigned short*)(ws + 51380224);
    unsigned long long* keys = (unsigned long long*)(ws + 51904512);
    int* counts      = (int*)(ws + 52166656);
    int* offsets     = (int*)(ws + 52170752);
    int* cursor      = (int*)(ws + 52174848);
    int* bucket      = (int*)(ws + 52178944);
    float* loss_part = (float*)(ws + 52310016);
    float* enorm     = (float*)(ws + 52342784);
    float* ws_total  = (float*)(ws + 52346880);

    k_split2<<<4480, 256, 0, stream>>>(x, emb, xh, xm, xl, eh, em, el,
                                       enorm, keys, counts);
    k_distm<<<2048, 256, 0, stream>>>(xh, xm, xl, eh, em, el, enorm, keys);
    k_scatter<<<NROWS / 4, 256, 0, stream>>>(x, emb, keys, out_q, out_tok,
                                             counts, loss_part);
    k_mid<<<1, 1024, 0, stream>>>(cs, counts, loss_part, out_loss, out_ncs,
                                  ws_total, offsets, cursor);
    k_bucket<<<NROWS / 256, 256, 0, stream>>>(keys, cursor, bucket);
    k_embpart<<<KCODES * 4, 256, 0, stream>>>(x, bucket, offsets, counts,
                                              partial);
    k_embfin2<<<KCODES, 256, 0, stream>>>(partial, avg, out_ncs, ws_total,
                                          out_emb, out_avg);
}